// Round 9
// baseline (352.980 us; speedup 1.0000x reference)
//
#include <hip/hip_runtime.h>
#include <hip/hip_fp16.h>
#include <math.h>

#define SCALING_F 0.46211715726000974f   // tanh(0.5)
#define MAXNORM_F 0.996f                 // 1 - BALL_EPS
#define MINNORM_F 1e-15f
#define BN_EPS_F  1e-5f

#define NBUCKET 32                       // BN-stat atomic spread buckets
#define CAP     64                       // slot capacity per node (mean deg 16)

typedef _Float16 v8h __attribute__((ext_vector_type(8)));
typedef float    v4f __attribute__((ext_vector_type(4)));

// reduce over the 16-lane group holding one row
__device__ __forceinline__ float rsum16(float v) {
  v += __shfl_xor(v, 1, 64);
  v += __shfl_xor(v, 2, 64);
  v += __shfl_xor(v, 4, 64);
  v += __shfl_xor(v, 8, 64);
  return v;
}

__device__ __forceinline__ void rsum16x6(float& a, float& b, float& c,
                                         float& d, float& e, float& f) {
#pragma unroll
  for (int o = 1; o <= 8; o <<= 1) {
    a += __shfl_xor(a, o, 64);
    b += __shfl_xor(b, o, 64);
    c += __shfl_xor(c, o, 64);
    d += __shfl_xor(d, o, 64);
    e += __shfl_xor(e, o, 64);
    f += __shfl_xor(f, o, 64);
  }
}

__device__ __forceinline__ float h2f(float v) {   // fp16 round-trip
  return __half2float(__float2half(v));
}

// accumulate 8 halfs (as uint4) into float[8]
__device__ __forceinline__ void acc8(float* a, uint4 u) {
  __half2 h0 = *(__half2*)&u.x;
  __half2 h1 = *(__half2*)&u.y;
  __half2 h2 = *(__half2*)&u.z;
  __half2 h3 = *(__half2*)&u.w;
  a[0] += __low2float(h0); a[1] += __high2float(h0);
  a[2] += __low2float(h1); a[3] += __high2float(h1);
  a[4] += __low2float(h2); a[5] += __high2float(h2);
  a[6] += __low2float(h3); a[7] += __high2float(h3);
}

// load 4 halfs (8B) -> float[4]
__device__ __forceinline__ void load4f(const __half* p, float* a) {
  uint2 u = *(const uint2*)p;
  __half2 h0 = *(__half2*)&u.x;
  __half2 h1 = *(__half2*)&u.y;
  a[0] = __low2float(h0); a[1] = __high2float(h0);
  a[2] = __low2float(h1); a[3] = __high2float(h1);
}

// ---------------------------------------------------------------------------
// zchain body (fused epilogue): per row, hyperbolic recurrence.
// ---------------------------------------------------------------------------
__device__ __forceinline__ void zchain_row(
    int row, int i, bool valid,
    const __half* __restrict__ X0, const __half* __restrict__ X1,
    const __half* __restrict__ X2, const __half* __restrict__ X3,
    __half* __restrict__ Xh)
{
  float x0[4] = {0,0,0,0}, x1[4] = {0,0,0,0}, x2[4] = {0,0,0,0}, x3[4] = {0,0,0,0};
  if (valid) {
    load4f(&X0[(size_t)row * 64 + 4 * i], x0);
    load4f(&X1[(size_t)row * 64 + 4 * i], x1);
    load4f(&X2[(size_t)row * 64 + 4 * i], x2);
    load4f(&X3[(size_t)row * 64 + 4 * i], x3);
  }

  float zc[4], zp[4] = {0.f, 0.f, 0.f, 0.f};
  {
    float sx = rsum16(x0[0]*x0[0] + x0[1]*x0[1] + x0[2]*x0[2] + x0[3]*x0[3]);
    float norm = fmaxf(sqrtf(sx), MINNORM_F);
    float s = ((norm > MAXNORM_F) ? (MAXNORM_F / norm) : 1.0f) * SCALING_F;
#pragma unroll
    for (int e = 0; e < 4; ++e) zc[e] = x0[e] * s;
  }

  const float* Xi[3] = {x1, x2, x3};
#pragma unroll
  for (int li = 0; li < 3; ++li) {
    const float* xv = Xi[li];

    float p1 = xv[0]*xv[0] + xv[1]*xv[1] + xv[2]*xv[2] + xv[3]*xv[3];
    float p2 = zc[0]*zc[0]+zc[1]*zc[1]+zc[2]*zc[2]+zc[3]*zc[3];
    float p3 = zp[0]*zp[0]+zp[1]*zp[1]+zp[2]*zp[2]+zp[3]*zp[3];
    float p4 = zp[0]*zc[0]+zp[1]*zc[1]+zp[2]*zc[2]+zp[3]*zc[3];
    float p5 = zp[0]*xv[0]+zp[1]*xv[1]+zp[2]*xv[2]+zp[3]*xv[3];
    float p6 = zc[0]*xv[0]+zc[1]*xv[1]+zc[2]*xv[2]+zc[3]*xv[3];
    rsum16x6(p1, p2, p3, p4, p5, p6);
    float zc63 = __shfl(zc[3], 15, 16);   // col 63 = lane 15, elem 3
    float zp63 = __shfl(zp[3], 15, 16);

    float nzc2 = fmaxf(p2, MINNORM_F);
    float icz  = 1.0f / nzc2;
    float na2  = p2 * icz * icz;
    float r2   = na2 - 1.0f;
    float a63  = zc63 * icz;

    float sxn = fmaxf(sqrtf(p1), MINNORM_F);
    float sc  = ((sxn > MAXNORM_F) ? (MAXNORM_F / sxn) : 1.0f) * SCALING_F;
    float Sch2   = sc * sc * p1;         // Σch² (ch63 = 0: col63 zeroed in X)
    float Szp_a  = p4 * icz;
    float Sa_ch  = sc * p6 * icz;
    float Szp_ch = sc * p5;
    float Su_a   = Szp_a - na2;
    float Su2    = p3 - 2.0f * Szp_a + na2;
    float nu2    = fmaxf(Su2, MINNORM_F);
    float t1     = r2 / nu2;
    float Szp22  = fmaxf(t1*t1*Su2 + 2.0f*t1*Su_a + na2, 0.0f);
    float npn    = fmaxf(sqrtf(Szp22), MINNORM_F);
    float ipn    = 1.0f / npn;
    float zp2_63 = t1 * (zp63 - a63) + a63;
    float Szp2ch = t1 * (Szp_ch - Sa_ch) + Sa_ch;
    float rdc    = -ipn * Szp2ch;
    float rdr    = 1.0f - 2.0f*ipn*zp2_63 + ipn*ipn*Szp22;
    float m2     = 2.0f * rdc / rdr;
    float Szp2a  = t1 * Su_a + na2;
    float Srr_a  = a63 - ipn * Szp2a;
    float Sc2a   = Sa_ch - m2 * Srr_a;
    float Sc22   = Sch2 - 2.0f*m2*rdc + m2*m2*rdr;
    float Sc2ma  = Sc22 - 2.0f*Sc2a + na2;
    float nu22   = fmaxf(Sc2ma, MINNORM_F);
    float t2     = r2 / nu22;

    float zn[4];
#pragma unroll
    for (int e = 0; e < 4; ++e) {
      float ai  = zc[e] * icz;
      float zp2 = t1 * (zp[e] - ai) + ai;
      float rri = ((i == 15 && e == 3) ? 1.0f : 0.0f) - ipn * zp2;
      float c2  = sc * xv[e] - m2 * rri;
      zn[e]     = t2 * (c2 - ai) + ai;
    }
#pragma unroll
    for (int e = 0; e < 4; ++e) { zp[e] = zc[e]; zc[e] = zn[e]; }
  }

  {
    float sz = rsum16(zc[0]*zc[0] + zc[1]*zc[1] + zc[2]*zc[2] + zc[3]*zc[3]);
    float yn  = fmaxf(sqrtf(sz), MINNORM_F);
    float t   = fminf(yn, 1.0f);
    float ath = 0.5f * logf((1.0f + t) / (1.0f - t));
    float wsc = ath / yn;
    if (valid) {
      __half hv[4];
      hv[0] = __float2half(zc[0] * wsc);
      hv[1] = __float2half(zc[1] * wsc);
      hv[2] = __float2half(zc[2] * wsc);
      hv[3] = __float2half(zc[3] * wsc);
      *(uint2*)&Xh[(size_t)row * 64 + 4 * i] = *(uint2*)hv;
    }
  }
}

// ---------------------------------------------------------------------------
// k_zero: zero cnt/gstat/ovf region + convert W0T (needed by k_front's mm0).
// ---------------------------------------------------------------------------
__global__ __launch_bounds__(256) void k_zero(
    const float* __restrict__ W0, __half* __restrict__ W0T,
    int* __restrict__ zbase, int zwords)
{
  int id = blockIdx.x * 256 + threadIdx.x;
  if (id < 64 * 128) {            // W0T[n][k], k<128
    int n = id >> 7, k = id & 127;
    W0T[id] = __float2half(W0[(size_t)k * 64 + n]);
  }
  const int stride = gridDim.x * 256;
  for (int z = id; z < zwords; z += stride) zbase[z] = 0;
}

// ---------------------------------------------------------------------------
// Fused front-end: [0,DBLK) slot-fill | [,+MBLK) mm0 | [,+GBLK) graph bounds
// | rest: W1T/W2T conversion. Slot fill counts AND scatters in one atomic
// pass; cnt keeps counting past CAP (doubles as deg[] for the fallback).
// ---------------------------------------------------------------------------
__global__ __launch_bounds__(256) void k_front(
    const float* __restrict__ A, const __half* __restrict__ BT,
    const float* __restrict__ bias, __half* __restrict__ X, int M,
    const int* __restrict__ src, const int* __restrict__ dst, int E,
    int* __restrict__ cnt, unsigned short* __restrict__ slots,
    int* __restrict__ ovf,
    const int* __restrict__ batch, int G, int* __restrict__ gstart,
    const float* __restrict__ cW1, const float* __restrict__ cW2, int L,
    __half* __restrict__ W1T, __half* __restrict__ W2T,
    int DBLK, int MBLK, int GBLK)
{
  int bx = blockIdx.x;
  const int tid = threadIdx.x;

  if (bx < DBLK) {                       // ---- slot-fill (critical path) ----
    int i0 = (bx * 256 + tid) * 4;
    if (i0 + 4 <= E) {
      int4 d = *(const int4*)&dst[i0];
      int4 s = *(const int4*)&src[i0];
      int p0 = atomicAdd(&cnt[d.x], 1);
      int p1 = atomicAdd(&cnt[d.y], 1);
      int p2 = atomicAdd(&cnt[d.z], 1);
      int p3 = atomicAdd(&cnt[d.w], 1);
      if (p0 < CAP) slots[(size_t)d.x * CAP + p0] = (unsigned short)s.x; else *ovf = 1;
      if (p1 < CAP) slots[(size_t)d.y * CAP + p1] = (unsigned short)s.y; else *ovf = 1;
      if (p2 < CAP) slots[(size_t)d.z * CAP + p2] = (unsigned short)s.z; else *ovf = 1;
      if (p3 < CAP) slots[(size_t)d.w * CAP + p3] = (unsigned short)s.w; else *ovf = 1;
    } else {
      for (int i = i0; i < E; ++i) {
        int dv = dst[i];
        int p = atomicAdd(&cnt[dv], 1);
        if (p < CAP) slots[(size_t)dv * CAP + p] = (unsigned short)src[i];
        else *ovf = 1;
      }
    }
    return;
  }
  bx -= DBLK;

  if (bx < MBLK) {                       // ---- mm0 ----
    const int w    = tid >> 6;
    const int lane = tid & 63;
    const int q    = lane >> 4;
    const int i    = lane & 15;
    const int rblk = bx * 64;
    const int arow = rblk + w * 16 + i;

    v4f acc[4];
#pragma unroll
    for (int t = 0; t < 4; ++t) acc[t] = (v4f){0.f, 0.f, 0.f, 0.f};

#pragma unroll
    for (int hh = 0; hh < 4; ++hh) {
      v8h af = (v8h){0, 0, 0, 0, 0, 0, 0, 0};
      if (arow < M) {
        const float* p = &A[(size_t)arow * 128 + hh * 32 + q * 8];
        float4 fa = *(const float4*)p;
        float4 fb = *(const float4*)(p + 4);
        af[0] = (_Float16)fa.x; af[1] = (_Float16)fa.y;
        af[2] = (_Float16)fa.z; af[3] = (_Float16)fa.w;
        af[4] = (_Float16)fb.x; af[5] = (_Float16)fb.y;
        af[6] = (_Float16)fb.z; af[7] = (_Float16)fb.w;
      }
#pragma unroll
      for (int t = 0; t < 4; ++t) {
        v8h bf = *(const v8h*)&BT[(size_t)(t * 16 + i) * 128 + hh * 32 + q * 8];
        acc[t] = __builtin_amdgcn_mfma_f32_16x16x32_f16(af, bf, acc[t], 0, 0, 0);
      }
    }

#pragma unroll
    for (int j = 0; j < 4; ++j) {
      int row = rblk + w * 16 + 4 * q + j;
      if (row >= M) continue;
#pragma unroll
      for (int t = 0; t < 4; ++t)
        X[(size_t)row * 64 + i + 16 * t] =
            __float2half(fmaxf(acc[t][j] + bias[i + 16 * t], 0.f));
    }
    return;
  }
  bx -= MBLK;

  if (bx < GBLK) {                       // ---- graph boundaries ----
    int r = bx * 256 + tid;
    if (r >= M) return;
    int b = batch[r];
    int prev = (r == 0) ? -1 : batch[r - 1];
    for (int g = prev + 1; g <= b; ++g) gstart[g] = r;
    if (r == M - 1)
      for (int g = b + 1; g <= G; ++g) gstart[g] = M;
    return;
  }
  bx -= GBLK;

  {                                      // ---- W1T/W2T conversion ----
    int id = bx * 256 + tid;
    if (id < L * 64 * 64) {
      int l = id >> 12, rem = id & 4095;
      int n = rem >> 6, k = rem & 63;
      W1T[id] = __float2half(cW1[(size_t)l * 4096 + k * 64 + n]);
      W2T[id] = __float2half(cW2[(size_t)l * 4096 + k * 64 + n]);
    }
  }
}

// ---------------------------------------------------------------------------
// Launder pass (k_pack3): full-line streaming copies of EVERYTHING the first
// layer1 touches after the atomic storm — slots->slots2, X0->X0L, cnt->cnt2.
// Pays line-state resolution once with 400K+ independent lanes instead of
// inside layer1's latency-bound gather chains. Unconditional (correct in
// both fast and fallback paths).
// ---------------------------------------------------------------------------
__global__ __launch_bounds__(256) void k_pack3(
    const uint4* __restrict__ slotsIn, uint4* __restrict__ slotsOut, int nS,
    const uint4* __restrict__ x0In,    uint4* __restrict__ x0Out,    int nX,
    const uint4* __restrict__ cntIn,   uint4* __restrict__ cntOut,   int nC)
{
  int i = blockIdx.x * 256 + threadIdx.x;
  if (i < nS) { slotsOut[i] = slotsIn[i]; return; }
  i -= nS;
  if (i < nX) { x0Out[i] = x0In[i]; return; }
  i -= nX;
  if (i < nC) cntOut[i] = cntIn[i];
}

// ---------------------------------------------------------------------------
// Overflow-fallback CSR build (early-exit when no slot overflowed).
// ---------------------------------------------------------------------------
__global__ __launch_bounds__(256) void k_scan1(const int* __restrict__ ovf,
                                               const int* __restrict__ deg, int N,
                                               int* rowptr, int* bsum) {
  if (*ovf == 0) return;
  __shared__ int s[256];
  int t = threadIdx.x;
  int i = blockIdx.x * 256 + t;
  int v = (i < N) ? deg[i] : 0;
  s[t] = v;
  __syncthreads();
  for (int d = 1; d < 256; d <<= 1) {
    int add = (t >= d) ? s[t - d] : 0;
    __syncthreads();
    s[t] += add;
    __syncthreads();
  }
  if (i < N) rowptr[i] = s[t] - v;
  if (t == 255) bsum[blockIdx.x] = s[255];
}

__global__ __launch_bounds__(256) void k_scan2(const int* __restrict__ ovf,
                                               const int* __restrict__ bsum, int NB, int* boff) {
  if (*ovf == 0) return;
  __shared__ int s[256];
  int t = threadIdx.x;
  int v = (t < NB) ? bsum[t] : 0;
  s[t] = v;
  __syncthreads();
  for (int d = 1; d < 256; d <<= 1) {
    int add = (t >= d) ? s[t - d] : 0;
    __syncthreads();
    s[t] += add;
    __syncthreads();
  }
  boff[t] = s[t] - v;
}

__global__ __launch_bounds__(256) void k_scan3(const int* __restrict__ ovf,
                                               int* rowptr, const int* __restrict__ boff,
                                               int* cursor, int N, int E) {
  if (*ovf == 0) return;
  int i = blockIdx.x * 256 + threadIdx.x;
  if (i < N) {
    int v = rowptr[i] + boff[blockIdx.x];
    rowptr[i] = v;
    cursor[i] = v;
  }
  if (i == 0) rowptr[N] = E;
}

__global__ __launch_bounds__(256) void k_fill(const int* __restrict__ ovf,
                                              const int* __restrict__ src,
                                              const int* __restrict__ dst, int E,
                                              int* cursor, unsigned short* __restrict__ csr) {
  if (*ovf == 0) return;
  int i0 = (blockIdx.x * 256 + threadIdx.x) * 4;
  if (i0 + 4 <= E) {
    int4 d = *(const int4*)&dst[i0];
    int4 s = *(const int4*)&src[i0];
    int p0 = atomicAdd(&cursor[d.x], 1);
    int p1 = atomicAdd(&cursor[d.y], 1);
    int p2 = atomicAdd(&cursor[d.z], 1);
    int p3 = atomicAdd(&cursor[d.w], 1);
    csr[p0] = (unsigned short)s.x;
    csr[p1] = (unsigned short)s.y;
    csr[p2] = (unsigned short)s.z;
    csr[p3] = (unsigned short)s.w;
  } else {
    for (int i = i0; i < E; ++i) {
      int p = atomicAdd(&cursor[dst[i]], 1);
      csr[p] = (unsigned short)src[i];
    }
  }
}

// ---------------------------------------------------------------------------
// K1 (16-row tile, MFMA): h = relu((x[r] + sum_nb x[nb]) @ W1 + b1).
// Cooperative gather: per round, the 8 slot-groups each take a DIFFERENT
// neighbor (8 neighbors/round, 100% lane utilization). Staged 32/16/8-wide
// rounds. Fast path reads fixed-stride slots (start = r*CAP, count=cnt[r]);
// fallback (ovf) walks classic CSR.
// ---------------------------------------------------------------------------
__global__ __launch_bounds__(256, 4) void k_layer1(
    const __half* __restrict__ x,
    const int* __restrict__ ovf, const int* __restrict__ cnt,
    const unsigned short* __restrict__ slots,
    const int* __restrict__ rowptr, const unsigned short* __restrict__ csr,
    const __half* __restrict__ BT,
    const float* __restrict__ bias, __half* __restrict__ h,
    float* __restrict__ gstatP, int M)
{
  __shared__ __half AsH[16][80];   // 160B rows (16B aligned)
  const int tid  = threadIdx.x;
  const int w    = tid >> 6;
  const int lane = tid & 63;
  const int q    = lane >> 4;
  const int i    = lane & 15;
  const int g8   = lane >> 3;      // neighbor slot 0..7
  const int i8   = lane & 7;       // col group: cols 8*i8 .. +8
  const int rblk = blockIdx.x * 16;

  const int r0 = rblk + w * 4 + 0;
  const int r1 = rblk + w * 4 + 1;
  const int r2 = rblk + w * 4 + 2;
  const int r3 = rblk + w * 4 + 3;
  const bool v0 = (r0 < M), v1 = (r1 < M), v2 = (r2 < M), v3 = (r3 < M);

  float a0[8] = {0.f,0.f,0.f,0.f,0.f,0.f,0.f,0.f};
  float a1[8] = {0.f,0.f,0.f,0.f,0.f,0.f,0.f,0.f};
  float a2[8] = {0.f,0.f,0.f,0.f,0.f,0.f,0.f,0.f};
  float a3[8] = {0.f,0.f,0.f,0.f,0.f,0.f,0.f,0.f};

  const unsigned short* idx;
  int c0 = 0, e0 = 0, c1 = 0, e1 = 0, c2 = 0, e2 = 0, c3 = 0, e3 = 0;
  if (*ovf == 0) {                       // slot fast path
    idx = slots;
    if (v0) { c0 = r0 * CAP; e0 = c0 + cnt[r0]; }
    if (v1) { c1 = r1 * CAP; e1 = c1 + cnt[r1]; }
    if (v2) { c2 = r2 * CAP; e2 = c2 + cnt[r2]; }
    if (v3) { c3 = r3 * CAP; e3 = c3 + cnt[r3]; }
  } else {                               // CSR fallback
    idx = csr;
    if (v0) { c0 = rowptr[r0]; e0 = rowptr[r0 + 1]; }
    if (v1) { c1 = rowptr[r1]; e1 = rowptr[r1 + 1]; }
    if (v2) { c2 = rowptr[r2]; e2 = rowptr[r2 + 1]; }
    if (v3) { c3 = rowptr[r3]; e3 = rowptr[r3 + 1]; }
  }

  if (v0 && g8 == 0) acc8(a0, *(const uint4*)&x[(size_t)r0 * 64 + 8 * i8]);
  if (v1 && g8 == 0) acc8(a1, *(const uint4*)&x[(size_t)r1 * 64 + 8 * i8]);
  if (v2 && g8 == 0) acc8(a2, *(const uint4*)&x[(size_t)r2 * 64 + 8 * i8]);
  if (v3 && g8 == 0) acc8(a3, *(const uint4*)&x[(size_t)r3 * 64 + 8 * i8]);

  // 32-wide main loop: 4 idx loads + 4 gathers per stream, 16 gathers in flight
  while ((c0 + 32 <= e0) | (c1 + 32 <= e1) | (c2 + 32 <= e2) | (c3 + 32 <= e3)) {
    const bool d0 = (c0 + 32 <= e0);
    const bool d1 = (c1 + 32 <= e1);
    const bool d2 = (c2 + 32 <= e2);
    const bool d3 = (c3 + 32 <= e3);
    int n0a=0,n0b=0,n0c=0,n0d=0, n1a=0,n1b=0,n1c=0,n1d=0;
    int n2a=0,n2b=0,n2c=0,n2d=0, n3a=0,n3b=0,n3c=0,n3d=0;
    if (d0) { n0a=idx[c0+g8]; n0b=idx[c0+8+g8]; n0c=idx[c0+16+g8]; n0d=idx[c0+24+g8]; }
    if (d1) { n1a=idx[c1+g8]; n1b=idx[c1+8+g8]; n1c=idx[c1+16+g8]; n1d=idx[c1+24+g8]; }
    if (d2) { n2a=idx[c2+g8]; n2b=idx[c2+8+g8]; n2c=idx[c2+16+g8]; n2d=idx[c2+24+g8]; }
    if (d3) { n3a=idx[c3+g8]; n3b=idx[c3+8+g8]; n3c=idx[c3+16+g8]; n3d=idx[c3+24+g8]; }
    uint4 u0a,u0b,u0c,u0d, u1a,u1b,u1c,u1d, u2a,u2b,u2c,u2d, u3a,u3b,u3c,u3d;
    if (d0) { u0a=*(const uint4*)&x[(size_t)n0a*64+8*i8]; u0b=*(const uint4*)&x[(size_t)n0b*64+8*i8];
              u0c=*(const uint4*)&x[(size_t)n0c*64+8*i8]; u0d=*(const uint4*)&x[(size_t)n0d*64+8*i8]; }
    if (d1) { u1a=*(const uint4*)&x[(size_t)n1a*64+8*i8]; u1b=*(const uint4*)&x[(size_t)n1b*64+8*i8];
              u1c=*(const uint4*)&x[(size_t)n1c*64+8*i8]; u1d=*(const uint4*)&x[(size_t)n1d*64+8*i8]; }
    if (d2) { u2a=*(const uint4*)&x[(size_t)n2a*64+8*i8]; u2b=*(const uint4*)&x[(size_t)n2b*64+8*i8];
              u2c=*(const uint4*)&x[(size_t)n2c*64+8*i8]; u2d=*(const uint4*)&x[(size_t)n2d*64+8*i8]; }
    if (d3) { u3a=*(const uint4*)&x[(size_t)n3a*64+8*i8]; u3b=*(const uint4*)&x[(size_t)n3b*64+8*i8];
              u3c=*(const uint4*)&x[(size_t)n3c*64+8*i8]; u3d=*(const uint4*)&x[(size_t)n3d*64+8*i8]; }
    if (d0) { acc8(a0,u0a); acc8(a0,u0b); acc8(a0,u0c); acc8(a0,u0d); c0 += 32; }
    if (d1) { acc8(a1,u1a); acc8(a1,u1b); acc8(a1,u1c); acc8(a1,u1d); c1 += 32; }
    if (d2) { acc8(a2,u2a); acc8(a2,u2b); acc8(a2,u2c); acc8(a2,u2d); c2 += 32; }
    if (d3) { acc8(a3,u3a); acc8(a3,u3b); acc8(a3,u3c); acc8(a3,u3d); c3 += 32; }
  }
  // 16-wide pass
  {
    const bool d0 = (c0 + 16 <= e0);
    const bool d1 = (c1 + 16 <= e1);
    const bool d2 = (c2 + 16 <= e2);
    const bool d3 = (c3 + 16 <= e3);
    int n0a=0,n0b=0, n1a=0,n1b=0, n2a=0,n2b=0, n3a=0,n3b=0;
    if (d0) { n0a = idx[c0 + g8]; n0b = idx[c0 + 8 + g8]; }
    if (d1) { n1a = idx[c1 + g8]; n1b = idx[c1 + 8 + g8]; }
    if (d2) { n2a = idx[c2 + g8]; n2b = idx[c2 + 8 + g8]; }
    if (d3) { n3a = idx[c3 + g8]; n3b = idx[c3 + 8 + g8]; }
    uint4 u0a,u0b,u1a,u1b,u2a,u2b,u3a,u3b;
    if (d0) { u0a=*(const uint4*)&x[(size_t)n0a*64+8*i8]; u0b=*(const uint4*)&x[(size_t)n0b*64+8*i8]; }
    if (d1) { u1a=*(const uint4*)&x[(size_t)n1a*64+8*i8]; u1b=*(const uint4*)&x[(size_t)n1b*64+8*i8]; }
    if (d2) { u2a=*(const uint4*)&x[(size_t)n2a*64+8*i8]; u2b=*(const uint4*)&x[(size_t)n2b*64+8*i8]; }
    if (d3) { u3a=*(const uint4*)&x[(size_t)n3a*64+8*i8]; u3b=*(const uint4*)&x[(size_t)n3b*64+8*i8]; }
    if (d0) { acc8(a0,u0a); acc8(a0,u0b); c0 += 16; }
    if (d1) { acc8(a1,u1a); acc8(a1,u1b); c1 += 16; }
    if (d2) { acc8(a2,u2a); acc8(a2,u2b); c2 += 16; }
    if (d3) { acc8(a3,u3a); acc8(a3,u3b); c3 += 16; }
  }
  // 8-wide pass
  {
    const bool d0 = (c0 + 8 <= e0);
    const bool d1 = (c1 + 8 <= e1);
    const bool d2 = (c2 + 8 <= e2);
    const bool d3 = (c3 + 8 <= e3);
    int n0 = 0, n1 = 0, n2 = 0, n3 = 0;
    if (d0) n0 = idx[c0 + g8];
    if (d1) n1 = idx[c1 + g8];
    if (d2) n2 = idx[c2 + g8];
    if (d3) n3 = idx[c3 + g8];
    uint4 u0, u1, u2, u3;
    if (d0) u0 = *(const uint4*)&x[(size_t)n0 * 64 + 8 * i8];
    if (d1) u1 = *(const uint4*)&x[(size_t)n1 * 64 + 8 * i8];
    if (d2) u2 = *(const uint4*)&x[(size_t)n2 * 64 + 8 * i8];
    if (d3) u3 = *(const uint4*)&x[(size_t)n3 * 64 + 8 * i8];
    if (d0) { acc8(a0, u0); c0 += 8; }
    if (d1) { acc8(a1, u1); c1 += 8; }
    if (d2) { acc8(a2, u2); c2 += 8; }
    if (d3) { acc8(a3, u3); c3 += 8; }
  }
  // remainder (< 8 per stream)
  {
    const int rem0 = e0 - c0;
    const int rem1 = e1 - c1;
    const int rem2 = e2 - c2;
    const int rem3 = e3 - c3;
    int n0 = 0, n1 = 0, n2 = 0, n3 = 0;
    if (g8 < rem0) n0 = idx[c0 + g8];
    if (g8 < rem1) n1 = idx[c1 + g8];
    if (g8 < rem2) n2 = idx[c2 + g8];
    if (g8 < rem3) n3 = idx[c3 + g8];
    uint4 u0, u1, u2, u3;
    if (g8 < rem0) u0 = *(const uint4*)&x[(size_t)n0 * 64 + 8 * i8];
    if (g8 < rem1) u1 = *(const uint4*)&x[(size_t)n1 * 64 + 8 * i8];
    if (g8 < rem2) u2 = *(const uint4*)&x[(size_t)n2 * 64 + 8 * i8];
    if (g8 < rem3) u3 = *(const uint4*)&x[(size_t)n3 * 64 + 8 * i8];
    if (g8 < rem0) acc8(a0, u0);
    if (g8 < rem1) acc8(a1, u1);
    if (g8 < rem2) acc8(a2, u2);
    if (g8 < rem3) acc8(a3, u3);
  }

  // fold neighbor-slot groups (g8) -> lanes 0..7 hold the row sums
#pragma unroll
  for (int k = 0; k < 8; ++k) {
#pragma unroll
    for (int o = 8; o <= 32; o <<= 1) {
      a0[k] += __shfl_xor(a0[k], o, 64);
      a1[k] += __shfl_xor(a1[k], o, 64);
      a2[k] += __shfl_xor(a2[k], o, 64);
      a3[k] += __shfl_xor(a3[k], o, 64);
    }
  }
  if (g8 == 0) {
    __half hv[8];
#pragma unroll
    for (int k = 0; k < 8; ++k) hv[k] = __float2half(a0[k]);
    *(uint4*)&AsH[w * 4 + 0][8 * i8] = *(uint4*)hv;
#pragma unroll
    for (int k = 0; k < 8; ++k) hv[k] = __float2half(a1[k]);
    *(uint4*)&AsH[w * 4 + 1][8 * i8] = *(uint4*)hv;
#pragma unroll
    for (int k = 0; k < 8; ++k) hv[k] = __float2half(a2[k]);
    *(uint4*)&AsH[w * 4 + 2][8 * i8] = *(uint4*)hv;
#pragma unroll
    for (int k = 0; k < 8; ++k) hv[k] = __float2half(a3[k]);
    *(uint4*)&AsH[w * 4 + 3][8 * i8] = *(uint4*)hv;
  }
  __syncthreads();

  // ---- MFMA phase: wave w computes rows 0..15 x cols [16w, 16w+16) ----
  v4f acc = (v4f){0.f, 0.f, 0.f, 0.f};
#pragma unroll
  for (int hh = 0; hh < 2; ++hh) {
    v8h af = *(const v8h*)&AsH[i][hh * 32 + q * 8];
    v8h bf = *(const v8h*)&BT[(size_t)(w * 16 + i) * 64 + hh * 32 + q * 8];
    acc = __builtin_amdgcn_mfma_f32_16x16x32_f16(af, bf, acc, 0, 0, 0);
  }

  const int col = w * 16 + i;
  float s = 0.f, qq = 0.f;
#pragma unroll
  for (int j = 0; j < 4; ++j) {
    int row = rblk + 4 * q + j;
    if (row >= M) continue;
    float v = h2f(fmaxf(acc[j] + bias[col], 0.f));
    h[(size_t)row * 64 + col] = __float2half(v);
    s += v;
    qq += v * v;
  }
  s  += __shfl_xor(s, 16, 64);  qq += __shfl_xor(qq, 16, 64);
  s  += __shfl_xor(s, 32, 64);  qq += __shfl_xor(qq, 32, 64);
  if (q == 0) {
    const int bkt = (blockIdx.x & (NBUCKET - 1)) * 128;
    atomicAdd(&gstatP[bkt + col], s);
    atomicAdd(&gstatP[bkt + 64 + col], qq);
  }
}

// ---------------------------------------------------------------------------
// K2 (64-row tile, MFMA): Xout = relu(BN(h) @ W2 + b2), col63 = 0.
// Prologue reduces the NBUCKET BN-stat buckets. Optional fused zchain
// epilogue (last layer).
// ---------------------------------------------------------------------------
__global__ __launch_bounds__(256) void k_layer2(
    const __half* __restrict__ A, const __half* __restrict__ BT,
    const float* __restrict__ bias,
    const float* __restrict__ gstat, const float* __restrict__ gamma,
    const float* __restrict__ beta,
    __half* __restrict__ Xout, int M,
    const __half* __restrict__ Z0, const __half* __restrict__ Z1,
    const __half* __restrict__ Z2, __half* __restrict__ Xh, int doZ)
{
  __shared__ float scl_s[64], shf_s[64];
  __shared__ float tmp[128];
  const int tid  = threadIdx.x;
  const int w    = tid >> 6;
  const int lane = tid & 63;
  const int q    = lane >> 4;
  const int i    = lane & 15;
  const int rblk = blockIdx.x * 64;
  const int arow = rblk + w * 16 + i;

  if (tid < 128) {
    float a = 0.f;
#pragma unroll
    for (int b2 = 0; b2 < NBUCKET; ++b2) a += gstat[b2 * 128 + tid];
    tmp[tid] = a;
  }
  __syncthreads();
  if (tid < 64) {
    float mu  = tmp[tid] / (float)M;
    float var = tmp[64 + tid] / (float)M - mu * mu;
    float sv  = gamma[tid] / sqrtf(var + BN_EPS_F);
    scl_s[tid] = sv;
    shf_s[tid] = beta[tid] - mu * sv;
  }
  __syncthreads();

  v4f acc[4];
#pragma unroll
  for (int t = 0; t < 4; ++t) acc[t] = (v4f){0.f, 0.f, 0.f, 0.f};
#pragma unroll
  for (int hh = 0; hh < 2; ++hh) {
    const int k0 = hh * 32 + q * 8;
    v8h af = (v8h){0, 0, 0, 0, 0, 0, 0, 0};
    {
      float hv[8] = {0,0,0,0,0,0,0,0};
      if (arow < M) {
        uint4 u = *(const uint4*)&A[(size_t)arow * 64 + k0];
        __half2 h0 = *(__half2*)&u.x;
        __half2 h1 = *(__half2*)&u.y;
        __half2 h2 = *(__half2*)&u.z;
        __half2 h3 = *(__half2*)&u.w;
        hv[0] = __low2float(h0); hv[1] = __high2float(h0);
        hv[2] = __low2float(h1); hv[3] = __high2float(h1);
        hv[4] = __low2float(h2); hv[5] = __high2float(h2);
        hv[6] = __low2float(h3); hv[7] = __high2float(h3);
      }
#pragma unroll
      for (int k = 0; k < 8; ++k)
        af[k] = (_Float16)fmaf(hv[k], scl_s[k0 + k], shf_s[k0 + k]);
    }
#pragma unroll
    for (int t = 0; t < 4; ++t) {
      v8h bf = *(const v8h*)&BT[(size_t)(t * 16 + i) * 64 + k0];
      acc[t] = __builtin_amdgcn_mfma_f32_16x16x32_f16(af, bf, acc[t], 0, 0, 0);
    }
  }

#pragma unroll
  for (int j = 0; j < 4; ++j) {
    int row = rblk + w * 16 + 4 * q + j;
    if (row >= M) continue;
#pragma unroll
    for (int t = 0; t < 4; ++t) {
      float v = fmaxf(acc[t][j] + bias[i + 16 * t], 0.f);
      if (i == 15 && t == 3) v = 0.f;   // col 63
      Xout[(size_t)row * 64 + i + 16 * t] = __float2half(v);
    }
  }

  if (doZ) {
    __syncthreads();                     // all rows of this block written
    const int g16  = tid >> 4;           // 16 groups of 16 lanes
    const int il   = tid & 15;
#pragma unroll
    for (int p = 0; p < 4; ++p) {
      int row = rblk + p * 16 + g16;
      zchain_row(row, il, row < M, Z0, Z1, Z2, Xout, Xh);
    }
  }
}

// ---------------------------------------------------------------------------
// Per-graph pooling (from Xh fp16, rows gstart[g]..gstart[g+1]) + MLP head
// ---------------------------------------------------------------------------
__global__ __launch_bounds__(128) void k_mlp(const __half* __restrict__ Xh,
                                             const int* __restrict__ gstart,
                                             const float* __restrict__ fc1W, const float* __restrict__ fc1b,
                                             const float* __restrict__ fc2W, const float* __restrict__ fc2b,
                                             const float* __restrict__ fc3W, const float* __restrict__ fc3b,
                                             float* __restrict__ out) {
  __shared__ float p2s[2][64];
  __shared__ float p[64], o1[128], o2[64], lg[10], red[2];
  int g = blockIdx.x, t = threadIdx.x;
  int beg = gstart[g], end = gstart[g + 1];
  {
    int half = t >> 6, c = t & 63;
    float a = 0.f;
    int r = beg + half;
    for (; r + 6 <= end; r += 8) {
      float v0 = __half2float(Xh[(size_t)(r + 0) * 64 + c]);
      float v1 = __half2float(Xh[(size_t)(r + 2) * 64 + c]);
      float v2 = __half2float(Xh[(size_t)(r + 4) * 64 + c]);
      float v3 = __half2float(Xh[(size_t)(r + 6) * 64 + c]);
      a += (v0 + v1) + (v2 + v3);
    }
    for (; r < end; r += 2) a += __half2float(Xh[(size_t)r * 64 + c]);
    p2s[half][c] = a;
  }
  __syncthreads();
  if (t < 64) p[t] = p2s[0][t] + p2s[1][t];
  __syncthreads();
  {
    float a = fc1b[t];
    for (int k = 0; k < 64; ++k) a = fmaf(p[k], fc1W[k * 128 + t], a);
    o1[t] = fmaxf(a, 0.f);
  }
  __syncthreads();
  if (t < 64) {
    float a = fc2b[t];
    for (int k = 0; k < 128; ++k) a = fmaf(o1[k], fc2W[k * 64 + t], a);
    o2[t] = fmaxf(a, 0.f);
  }
  __syncthreads();
  if (t < 10) {
    float a = fc3b[t];
    for (int k = 0; k < 64; ++k) a = fmaf(o2[k], fc3W[k * 10 + t], a);
    lg[t] = a;
  }
  __syncthreads();
  if (t == 0) {
    float mx = lg[0];
    for (int j = 1; j < 10; ++j) mx = fmaxf(mx, lg[j]);
    float s = 0.f;
    for (int j = 0; j < 10; ++j) s += expf(lg[j] - mx);
    red[0] = mx;
    red[1] = logf(s);
  }
  __syncthreads();
  if (t < 10) out[(size_t)g * 10 + t] = lg[t] - red[0] - red[1];
}

// ---------------------------------------------------------------------------
extern "C" void kernel_launch(void* const* d_in, const int* in_sizes, int n_in,
                              void* d_out, int out_size, void* d_ws, size_t ws_size,
                              hipStream_t stream) {
  const float* x_in  = (const float*)d_in[0];
  const int*   ei    = (const int*)d_in[1];
  const int*   batch = (const int*)d_in[2];
  const float* W0    = (const float*)d_in[3];
  const float* b0    = (const float*)d_in[4];
  const float* cW1   = (const float*)d_in[5];
  const float* cb1   = (const float*)d_in[6];
  const float* gamma = (const float*)d_in[7];
  const float* beta  = (const float*)d_in[8];
  const float* cW2   = (const float*)d_in[9];
  const float* cb2   = (const float*)d_in[10];
  const float* fc1W  = (const float*)d_in[11];
  const float* fc1b  = (const float*)d_in[12];
  const float* fc2W  = (const float*)d_in[13];
  const float* fc2b  = (const float*)d_in[14];
  const float* fc3W  = (const float*)d_in[15];
  const float* fc3b  = (const float*)d_in[16];
  float* out = (float*)d_out;

  const int N = in_sizes[0] / 128;
  const int E = in_sizes[1] / 2;
  const int L = in_sizes[5] / (64 * 64);
  const int G = out_size / 10;
  const int* src = ei;
  const int* dst = ei + E;

  char* ws = (char*)d_ws;
  size_t off = 0;
  auto alloc = [&](size_t bytes) -> char* {
    char* p = ws + off;
    off += (bytes + 255) & ~(size_t)255;
    return p;
  };
  __half* X0  = (__half*)alloc((size_t)N * 64 * 2);
  __half* X0L = (__half*)alloc((size_t)N * 64 * 2);   // laundered X0
  __half* X1  = (__half*)alloc((size_t)N * 64 * 2);
  __half* X2  = (__half*)alloc((size_t)N * 64 * 2);
  __half* X3  = (__half*)alloc((size_t)N * 64 * 2);
  __half* Bf  = (__half*)alloc((size_t)N * 64 * 2);
  __half* Xh  = (__half*)alloc((size_t)N * 64 * 2);
  __half* W0T = (__half*)alloc((size_t)64 * 128 * 2);
  __half* W1T = (__half*)alloc((size_t)L * 64 * 64 * 2);
  __half* W2T = (__half*)alloc((size_t)L * 64 * 64 * 2);
  int*    gstart = (int*)alloc((size_t)(G + 1) * 4);
  // ---- zeroed region: cnt, gstatAll, ovf (contiguous, zeroed by k_zero) ----
  int*   cnt  = (int*)alloc((size_t)N * 4);
  float* gstatAll = (float*)alloc((size_t)3 * NBUCKET * 128 * 4);
  int*   ovf  = (int*)alloc(256);        // one flag (padded)
  char*  zero_end = ws + off;
  // -------------------------------------------------------------------------
  int*   cnt2 = (int*)alloc((size_t)N * 4);           // laundered cnt
  unsigned short* slots  = (unsigned short*)alloc((size_t)N * CAP * 2);
  unsigned short* slots2 = (unsigned short*)alloc((size_t)N * CAP * 2);
  int*   rowptr = (int*)alloc((size_t)(N + 1) * 4);
  int*   cursor = (int*)alloc((size_t)N * 4);
  unsigned short* csr = (unsigned short*)alloc((size_t)E * 2);
  int*   bsum   = (int*)alloc(256 * 4);
  int*   boff   = (int*)alloc(256 * 4);
  __half* Xs[4] = {X0L, X1, X2, X3};     // downstream consumers use laundered X0

  const int zwords = (int)((zero_end - (char*)cnt) / 4);

  const int mmGrid    = (N + 63) / 64;
  const int l1Grid    = (N + 15) / 16;
  const int edge4Grid = (E / 4 + 255) / 256 + 1;
  const int gbGrid    = (N + 255) / 256;
  const int wBlk      = (L * 4096 + 255) / 256;
  const int nS16      = N * CAP * 2 / 16;             // uint4 count: slots
  const int nX16      = N * 64 * 2 / 16;              // uint4 count: X0
  const int nC16      = (N * 4 + 15) / 16;            // uint4 count: cnt
  const int packGrid  = (nS16 + nX16 + nC16 + 255) / 256;

  // zero cnt/gstat/ovf + convert W0T (needed by k_front's mm0 section)
  k_zero<<<256, 256, 0, stream>>>(W0, W0T, cnt, zwords);

  // fused front-end: slot-fill | mm0 | gb | W1T/W2T cvt in one dispatch
  k_front<<<edge4Grid + mmGrid + gbGrid + wBlk, 256, 0, stream>>>(
      x_in, W0T, b0, X0, N,
      src, dst, E, cnt, slots, ovf,
      batch, G, gstart,
      cW1, cW2, L, W1T, W2T,
      edge4Grid, mmGrid, gbGrid);

  // launder everything the first layer1 touches: slots, X0, cnt
  k_pack3<<<packGrid, 256, 0, stream>>>(
      (const uint4*)slots, (uint4*)slots2, nS16,
      (const uint4*)X0,    (uint4*)X0L,    nX16,
      (const uint4*)cnt,   (uint4*)cnt2,   nC16);

  // overflow fallback chain (early-exit when ovf == 0)
  const int NB = (N + 255) / 256;
  k_scan1<<<NB, 256, 0, stream>>>(ovf, cnt, N, rowptr, bsum);
  k_scan2<<<1, 256, 0, stream>>>(ovf, bsum, NB, boff);
  k_scan3<<<NB, 256, 0, stream>>>(ovf, rowptr, boff, cursor, N, E);
  k_fill<<<edge4Grid, 256, 0, stream>>>(ovf, src, dst, E, cursor, csr);

  for (int i = 0; i < L; ++i) {
    float* gstat = gstatAll + (size_t)i * NBUCKET * 128;
    const int doZ = (i == L - 1) ? 1 : 0;
    k_layer1<<<l1Grid, 256, 0, stream>>>(Xs[i], ovf, cnt2, slots2, rowptr, csr,
                                         W1T + (size_t)i * 4096, cb1 + i * 64,
                                         Bf, gstat, N);
    k_layer2<<<mmGrid, 256, 0, stream>>>(Bf, W2T + (size_t)i * 4096, cb2 + i * 64,
                                         gstat, gamma + i * 64, beta + i * 64,
                                         Xs[i + 1], N,
                                         Xs[0], X1, X2, Xh, doZ);
  }

  k_mlp<<<G, 128, 0, stream>>>(Xh, gstart, fc1W, fc1b, fc2W, fc2b, fc3W, fc3b, out);
}

// Round 10
// 339.391 us; speedup vs baseline: 1.0400x; 1.0400x over previous
//
#include <hip/hip_runtime.h>
#include <hip/hip_fp16.h>
#include <math.h>

#define SCALING_F 0.46211715726000974f   // tanh(0.5)
#define MAXNORM_F 0.996f                 // 1 - BALL_EPS
#define MINNORM_F 1e-15f
#define BN_EPS_F  1e-5f

#define NBUCKET 32                       // BN-stat atomic spread buckets
#define CAP     64                       // slot capacity per node (mean deg 16)

typedef _Float16 v8h __attribute__((ext_vector_type(8)));
typedef float    v4f __attribute__((ext_vector_type(4)));

// reduce over the 16-lane group holding one row
__device__ __forceinline__ float rsum16(float v) {
  v += __shfl_xor(v, 1, 64);
  v += __shfl_xor(v, 2, 64);
  v += __shfl_xor(v, 4, 64);
  v += __shfl_xor(v, 8, 64);
  return v;
}

__device__ __forceinline__ void rsum16x6(float& a, float& b, float& c,
                                         float& d, float& e, float& f) {
#pragma unroll
  for (int o = 1; o <= 8; o <<= 1) {
    a += __shfl_xor(a, o, 64);
    b += __shfl_xor(b, o, 64);
    c += __shfl_xor(c, o, 64);
    d += __shfl_xor(d, o, 64);
    e += __shfl_xor(e, o, 64);
    f += __shfl_xor(f, o, 64);
  }
}

__device__ __forceinline__ float h2f(float v) {   // fp16 round-trip
  return __half2float(__float2half(v));
}

// accumulate 8 halfs (as uint4) into float[8]
__device__ __forceinline__ void acc8(float* a, uint4 u) {
  __half2 h0 = *(__half2*)&u.x;
  __half2 h1 = *(__half2*)&u.y;
  __half2 h2 = *(__half2*)&u.z;
  __half2 h3 = *(__half2*)&u.w;
  a[0] += __low2float(h0); a[1] += __high2float(h0);
  a[2] += __low2float(h1); a[3] += __high2float(h1);
  a[4] += __low2float(h2); a[5] += __high2float(h2);
  a[6] += __low2float(h3); a[7] += __high2float(h3);
}

// load 4 halfs (8B) -> float[4]
__device__ __forceinline__ void load4f(const __half* p, float* a) {
  uint2 u = *(const uint2*)p;
  __half2 h0 = *(__half2*)&u.x;
  __half2 h1 = *(__half2*)&u.y;
  a[0] = __low2float(h0); a[1] = __high2float(h0);
  a[2] = __low2float(h1); a[3] = __high2float(h1);
}

// ---------------------------------------------------------------------------
// zchain body (fused epilogue): per row, hyperbolic recurrence.
// ---------------------------------------------------------------------------
__device__ __forceinline__ void zchain_row(
    int row, int i, bool valid,
    const __half* __restrict__ X0, const __half* __restrict__ X1,
    const __half* __restrict__ X2, const __half* __restrict__ X3,
    __half* __restrict__ Xh)
{
  float x0[4] = {0,0,0,0}, x1[4] = {0,0,0,0}, x2[4] = {0,0,0,0}, x3[4] = {0,0,0,0};
  if (valid) {
    load4f(&X0[(size_t)row * 64 + 4 * i], x0);
    load4f(&X1[(size_t)row * 64 + 4 * i], x1);
    load4f(&X2[(size_t)row * 64 + 4 * i], x2);
    load4f(&X3[(size_t)row * 64 + 4 * i], x3);
  }

  float zc[4], zp[4] = {0.f, 0.f, 0.f, 0.f};
  {
    float sx = rsum16(x0[0]*x0[0] + x0[1]*x0[1] + x0[2]*x0[2] + x0[3]*x0[3]);
    float norm = fmaxf(sqrtf(sx), MINNORM_F);
    float s = ((norm > MAXNORM_F) ? (MAXNORM_F / norm) : 1.0f) * SCALING_F;
#pragma unroll
    for (int e = 0; e < 4; ++e) zc[e] = x0[e] * s;
  }

  const float* Xi[3] = {x1, x2, x3};
#pragma unroll
  for (int li = 0; li < 3; ++li) {
    const float* xv = Xi[li];

    float p1 = xv[0]*xv[0] + xv[1]*xv[1] + xv[2]*xv[2] + xv[3]*xv[3];
    float p2 = zc[0]*zc[0]+zc[1]*zc[1]+zc[2]*zc[2]+zc[3]*zc[3];
    float p3 = zp[0]*zp[0]+zp[1]*zp[1]+zp[2]*zp[2]+zp[3]*zp[3];
    float p4 = zp[0]*zc[0]+zp[1]*zc[1]+zp[2]*zc[2]+zp[3]*zc[3];
    float p5 = zp[0]*xv[0]+zp[1]*xv[1]+zp[2]*xv[2]+zp[3]*xv[3];
    float p6 = zc[0]*xv[0]+zc[1]*xv[1]+zc[2]*xv[2]+zc[3]*xv[3];
    rsum16x6(p1, p2, p3, p4, p5, p6);
    float zc63 = __shfl(zc[3], 15, 16);   // col 63 = lane 15, elem 3
    float zp63 = __shfl(zp[3], 15, 16);

    float nzc2 = fmaxf(p2, MINNORM_F);
    float icz  = 1.0f / nzc2;
    float na2  = p2 * icz * icz;
    float r2   = na2 - 1.0f;
    float a63  = zc63 * icz;

    float sxn = fmaxf(sqrtf(p1), MINNORM_F);
    float sc  = ((sxn > MAXNORM_F) ? (MAXNORM_F / sxn) : 1.0f) * SCALING_F;
    float Sch2   = sc * sc * p1;         // Σch² (ch63 = 0: col63 zeroed in X)
    float Szp_a  = p4 * icz;
    float Sa_ch  = sc * p6 * icz;
    float Szp_ch = sc * p5;
    float Su_a   = Szp_a - na2;
    float Su2    = p3 - 2.0f * Szp_a + na2;
    float nu2    = fmaxf(Su2, MINNORM_F);
    float t1     = r2 / nu2;
    float Szp22  = fmaxf(t1*t1*Su2 + 2.0f*t1*Su_a + na2, 0.0f);
    float npn    = fmaxf(sqrtf(Szp22), MINNORM_F);
    float ipn    = 1.0f / npn;
    float zp2_63 = t1 * (zp63 - a63) + a63;
    float Szp2ch = t1 * (Szp_ch - Sa_ch) + Sa_ch;
    float rdc    = -ipn * Szp2ch;
    float rdr    = 1.0f - 2.0f*ipn*zp2_63 + ipn*ipn*Szp22;
    float m2     = 2.0f * rdc / rdr;
    float Szp2a  = t1 * Su_a + na2;
    float Srr_a  = a63 - ipn * Szp2a;
    float Sc2a   = Sa_ch - m2 * Srr_a;
    float Sc22   = Sch2 - 2.0f*m2*rdc + m2*m2*rdr;
    float Sc2ma  = Sc22 - 2.0f*Sc2a + na2;
    float nu22   = fmaxf(Sc2ma, MINNORM_F);
    float t2     = r2 / nu22;

    float zn[4];
#pragma unroll
    for (int e = 0; e < 4; ++e) {
      float ai  = zc[e] * icz;
      float zp2 = t1 * (zp[e] - ai) + ai;
      float rri = ((i == 15 && e == 3) ? 1.0f : 0.0f) - ipn * zp2;
      float c2  = sc * xv[e] - m2 * rri;
      zn[e]     = t2 * (c2 - ai) + ai;
    }
#pragma unroll
    for (int e = 0; e < 4; ++e) { zp[e] = zc[e]; zc[e] = zn[e]; }
  }

  {
    float sz = rsum16(zc[0]*zc[0] + zc[1]*zc[1] + zc[2]*zc[2] + zc[3]*zc[3]);
    float yn  = fmaxf(sqrtf(sz), MINNORM_F);
    float t   = fminf(yn, 1.0f);
    float ath = 0.5f * logf((1.0f + t) / (1.0f - t));
    float wsc = ath / yn;
    if (valid) {
      __half hv[4];
      hv[0] = __float2half(zc[0] * wsc);
      hv[1] = __float2half(zc[1] * wsc);
      hv[2] = __float2half(zc[2] * wsc);
      hv[3] = __float2half(zc[3] * wsc);
      *(uint2*)&Xh[(size_t)row * 64 + 4 * i] = *(uint2*)hv;
    }
  }
}

// ---------------------------------------------------------------------------
// k_zero: zero cnt/gstat/ovf region + convert W0T (needed by k_front's mm0).
// ---------------------------------------------------------------------------
__global__ __launch_bounds__(256) void k_zero(
    const float* __restrict__ W0, __half* __restrict__ W0T,
    int* __restrict__ zbase, int zwords)
{
  int id = blockIdx.x * 256 + threadIdx.x;
  if (id < 64 * 128) {            // W0T[n][k], k<128
    int n = id >> 7, k = id & 127;
    W0T[id] = __float2half(W0[(size_t)k * 64 + n]);
  }
  const int stride = gridDim.x * 256;
  for (int z = id; z < zwords; z += stride) zbase[z] = 0;
}

// ---------------------------------------------------------------------------
// Fused front-end: [0,DBLK) XCD-partitioned slot-fill | [,+MBLK) mm0 |
// [,+GBLK) graph bounds | rest: W1T/W2T conversion.
// Slot-fill is replicated 8x: block bx -> xcd = bx&7, chunk = bx>>3. Each
// block scans its 1024-edge window (edge list is L3-resident after replica
// 0) and handles ONLY dst in slice [xcd*N/8,(xcd+1)*N/8). With round-robin
// blockIdx->XCD mapping, each 0.8MB slots slice + 25KB cnt slice is written
// from a single XCD -> scatter stays L2-local, no cross-XCD line migration
// (round-9 counters: WRITE_SIZE 51MB = 800K x 64B dirty-line amplification).
// Mapping is a locality heuristic only — correctness is mapping-independent.
// ---------------------------------------------------------------------------
__global__ __launch_bounds__(256) void k_front(
    const float* __restrict__ A, const __half* __restrict__ BT,
    const float* __restrict__ bias, __half* __restrict__ X, int M,
    const int* __restrict__ src, const int* __restrict__ dst, int E,
    int* __restrict__ cnt, unsigned short* __restrict__ slots,
    int* __restrict__ ovf,
    const int* __restrict__ batch, int G, int* __restrict__ gstart,
    const float* __restrict__ cW1, const float* __restrict__ cW2, int L,
    __half* __restrict__ W1T, __half* __restrict__ W2T,
    int DBLK, int MBLK, int GBLK)
{
  int bx = blockIdx.x;
  const int tid = threadIdx.x;

  if (bx < DBLK) {                       // ---- XCD-partitioned slot-fill ----
    const int xcd   = bx & 7;
    const int chunk = bx >> 3;
    const int per   = (M + 7) >> 3;
    const int lo    = xcd * per;
    const int hi    = (lo + per < M) ? (lo + per) : M;
    int i0 = (chunk * 256 + tid) * 4;
    if (i0 + 4 <= E) {
      int4 d = *(const int4*)&dst[i0];
      int4 s = *(const int4*)&src[i0];
      if (d.x >= lo && d.x < hi) {
        int p = atomicAdd(&cnt[d.x], 1);
        if (p < CAP) slots[(size_t)d.x * CAP + p] = (unsigned short)s.x; else *ovf = 1;
      }
      if (d.y >= lo && d.y < hi) {
        int p = atomicAdd(&cnt[d.y], 1);
        if (p < CAP) slots[(size_t)d.y * CAP + p] = (unsigned short)s.y; else *ovf = 1;
      }
      if (d.z >= lo && d.z < hi) {
        int p = atomicAdd(&cnt[d.z], 1);
        if (p < CAP) slots[(size_t)d.z * CAP + p] = (unsigned short)s.z; else *ovf = 1;
      }
      if (d.w >= lo && d.w < hi) {
        int p = atomicAdd(&cnt[d.w], 1);
        if (p < CAP) slots[(size_t)d.w * CAP + p] = (unsigned short)s.w; else *ovf = 1;
      }
    } else {
      for (int i = i0; i < E; ++i) {
        int dv = dst[i];
        if (dv >= lo && dv < hi) {
          int p = atomicAdd(&cnt[dv], 1);
          if (p < CAP) slots[(size_t)dv * CAP + p] = (unsigned short)src[i];
          else *ovf = 1;
        }
      }
    }
    return;
  }
  bx -= DBLK;

  if (bx < MBLK) {                       // ---- mm0 ----
    const int w    = tid >> 6;
    const int lane = tid & 63;
    const int q    = lane >> 4;
    const int i    = lane & 15;
    const int rblk = bx * 64;
    const int arow = rblk + w * 16 + i;

    v4f acc[4];
#pragma unroll
    for (int t = 0; t < 4; ++t) acc[t] = (v4f){0.f, 0.f, 0.f, 0.f};

#pragma unroll
    for (int hh = 0; hh < 4; ++hh) {
      v8h af = (v8h){0, 0, 0, 0, 0, 0, 0, 0};
      if (arow < M) {
        const float* p = &A[(size_t)arow * 128 + hh * 32 + q * 8];
        float4 fa = *(const float4*)p;
        float4 fb = *(const float4*)(p + 4);
        af[0] = (_Float16)fa.x; af[1] = (_Float16)fa.y;
        af[2] = (_Float16)fa.z; af[3] = (_Float16)fa.w;
        af[4] = (_Float16)fb.x; af[5] = (_Float16)fb.y;
        af[6] = (_Float16)fb.z; af[7] = (_Float16)fb.w;
      }
#pragma unroll
      for (int t = 0; t < 4; ++t) {
        v8h bf = *(const v8h*)&BT[(size_t)(t * 16 + i) * 128 + hh * 32 + q * 8];
        acc[t] = __builtin_amdgcn_mfma_f32_16x16x32_f16(af, bf, acc[t], 0, 0, 0);
      }
    }

#pragma unroll
    for (int j = 0; j < 4; ++j) {
      int row = rblk + w * 16 + 4 * q + j;
      if (row >= M) continue;
#pragma unroll
      for (int t = 0; t < 4; ++t)
        X[(size_t)row * 64 + i + 16 * t] =
            __float2half(fmaxf(acc[t][j] + bias[i + 16 * t], 0.f));
    }
    return;
  }
  bx -= MBLK;

  if (bx < GBLK) {                       // ---- graph boundaries ----
    int r = bx * 256 + tid;
    if (r >= M) return;
    int b = batch[r];
    int prev = (r == 0) ? -1 : batch[r - 1];
    for (int g = prev + 1; g <= b; ++g) gstart[g] = r;
    if (r == M - 1)
      for (int g = b + 1; g <= G; ++g) gstart[g] = M;
    return;
  }
  bx -= GBLK;

  {                                      // ---- W1T/W2T conversion ----
    int id = bx * 256 + tid;
    if (id < L * 64 * 64) {
      int l = id >> 12, rem = id & 4095;
      int n = rem >> 6, k = rem & 63;
      W1T[id] = __float2half(cW1[(size_t)l * 4096 + k * 64 + n]);
      W2T[id] = __float2half(cW2[(size_t)l * 4096 + k * 64 + n]);
    }
  }
}

// ---------------------------------------------------------------------------
// Launder pass (k_pack3): full-line streaming copies of EVERYTHING the first
// layer1 touches after the atomic storm — slots->slots2, X0->X0L, cnt->cnt2.
// ---------------------------------------------------------------------------
__global__ __launch_bounds__(256) void k_pack3(
    const uint4* __restrict__ slotsIn, uint4* __restrict__ slotsOut, int nS,
    const uint4* __restrict__ x0In,    uint4* __restrict__ x0Out,    int nX,
    const uint4* __restrict__ cntIn,   uint4* __restrict__ cntOut,   int nC)
{
  int i = blockIdx.x * 256 + threadIdx.x;
  if (i < nS) { slotsOut[i] = slotsIn[i]; return; }
  i -= nS;
  if (i < nX) { x0Out[i] = x0In[i]; return; }
  i -= nX;
  if (i < nC) cntOut[i] = cntIn[i];
}

// ---------------------------------------------------------------------------
// Overflow-fallback CSR build (early-exit when no slot overflowed).
// ---------------------------------------------------------------------------
__global__ __launch_bounds__(256) void k_scan1(const int* __restrict__ ovf,
                                               const int* __restrict__ deg, int N,
                                               int* rowptr, int* bsum) {
  if (*ovf == 0) return;
  __shared__ int s[256];
  int t = threadIdx.x;
  int i = blockIdx.x * 256 + t;
  int v = (i < N) ? deg[i] : 0;
  s[t] = v;
  __syncthreads();
  for (int d = 1; d < 256; d <<= 1) {
    int add = (t >= d) ? s[t - d] : 0;
    __syncthreads();
    s[t] += add;
    __syncthreads();
  }
  if (i < N) rowptr[i] = s[t] - v;
  if (t == 255) bsum[blockIdx.x] = s[255];
}

__global__ __launch_bounds__(256) void k_scan2(const int* __restrict__ ovf,
                                               const int* __restrict__ bsum, int NB, int* boff) {
  if (*ovf == 0) return;
  __shared__ int s[256];
  int t = threadIdx.x;
  int v = (t < NB) ? bsum[t] : 0;
  s[t] = v;
  __syncthreads();
  for (int d = 1; d < 256; d <<= 1) {
    int add = (t >= d) ? s[t - d] : 0;
    __syncthreads();
    s[t] += add;
    __syncthreads();
  }
  boff[t] = s[t] - v;
}

__global__ __launch_bounds__(256) void k_scan3(const int* __restrict__ ovf,
                                               int* rowptr, const int* __restrict__ boff,
                                               int* cursor, int N, int E) {
  if (*ovf == 0) return;
  int i = blockIdx.x * 256 + threadIdx.x;
  if (i < N) {
    int v = rowptr[i] + boff[blockIdx.x];
    rowptr[i] = v;
    cursor[i] = v;
  }
  if (i == 0) rowptr[N] = E;
}

__global__ __launch_bounds__(256) void k_fill(const int* __restrict__ ovf,
                                              const int* __restrict__ src,
                                              const int* __restrict__ dst, int E,
                                              int* cursor, unsigned short* __restrict__ csr) {
  if (*ovf == 0) return;
  int i0 = (blockIdx.x * 256 + threadIdx.x) * 4;
  if (i0 + 4 <= E) {
    int4 d = *(const int4*)&dst[i0];
    int4 s = *(const int4*)&src[i0];
    int p0 = atomicAdd(&cursor[d.x], 1);
    int p1 = atomicAdd(&cursor[d.y], 1);
    int p2 = atomicAdd(&cursor[d.z], 1);
    int p3 = atomicAdd(&cursor[d.w], 1);
    csr[p0] = (unsigned short)s.x;
    csr[p1] = (unsigned short)s.y;
    csr[p2] = (unsigned short)s.z;
    csr[p3] = (unsigned short)s.w;
  } else {
    for (int i = i0; i < E; ++i) {
      int p = atomicAdd(&cursor[dst[i]], 1);
      csr[p] = (unsigned short)src[i];
    }
  }
}

// ---------------------------------------------------------------------------
// K1 (16-row tile, MFMA): h = relu((x[r] + sum_nb x[nb]) @ W1 + b1).
// Cooperative gather: per round, the 8 slot-groups each take a DIFFERENT
// neighbor (8 neighbors/round, 100% lane utilization). Staged 32/16/8-wide
// rounds. Fast path reads fixed-stride slots (start = r*CAP, count=cnt[r]);
// fallback (ovf) walks classic CSR.
// ---------------------------------------------------------------------------
__global__ __launch_bounds__(256, 4) void k_layer1(
    const __half* __restrict__ x,
    const int* __restrict__ ovf, const int* __restrict__ cnt,
    const unsigned short* __restrict__ slots,
    const int* __restrict__ rowptr, const unsigned short* __restrict__ csr,
    const __half* __restrict__ BT,
    const float* __restrict__ bias, __half* __restrict__ h,
    float* __restrict__ gstatP, int M)
{
  __shared__ __half AsH[16][80];   // 160B rows (16B aligned)
  const int tid  = threadIdx.x;
  const int w    = tid >> 6;
  const int lane = tid & 63;
  const int q    = lane >> 4;
  const int i    = lane & 15;
  const int g8   = lane >> 3;      // neighbor slot 0..7
  const int i8   = lane & 7;       // col group: cols 8*i8 .. +8
  const int rblk = blockIdx.x * 16;

  const int r0 = rblk + w * 4 + 0;
  const int r1 = rblk + w * 4 + 1;
  const int r2 = rblk + w * 4 + 2;
  const int r3 = rblk + w * 4 + 3;
  const bool v0 = (r0 < M), v1 = (r1 < M), v2 = (r2 < M), v3 = (r3 < M);

  float a0[8] = {0.f,0.f,0.f,0.f,0.f,0.f,0.f,0.f};
  float a1[8] = {0.f,0.f,0.f,0.f,0.f,0.f,0.f,0.f};
  float a2[8] = {0.f,0.f,0.f,0.f,0.f,0.f,0.f,0.f};
  float a3[8] = {0.f,0.f,0.f,0.f,0.f,0.f,0.f,0.f};

  const unsigned short* idx;
  int c0 = 0, e0 = 0, c1 = 0, e1 = 0, c2 = 0, e2 = 0, c3 = 0, e3 = 0;
  if (*ovf == 0) {                       // slot fast path
    idx = slots;
    if (v0) { c0 = r0 * CAP; e0 = c0 + cnt[r0]; }
    if (v1) { c1 = r1 * CAP; e1 = c1 + cnt[r1]; }
    if (v2) { c2 = r2 * CAP; e2 = c2 + cnt[r2]; }
    if (v3) { c3 = r3 * CAP; e3 = c3 + cnt[r3]; }
  } else {                               // CSR fallback
    idx = csr;
    if (v0) { c0 = rowptr[r0]; e0 = rowptr[r0 + 1]; }
    if (v1) { c1 = rowptr[r1]; e1 = rowptr[r1 + 1]; }
    if (v2) { c2 = rowptr[r2]; e2 = rowptr[r2 + 1]; }
    if (v3) { c3 = rowptr[r3]; e3 = rowptr[r3 + 1]; }
  }

  if (v0 && g8 == 0) acc8(a0, *(const uint4*)&x[(size_t)r0 * 64 + 8 * i8]);
  if (v1 && g8 == 0) acc8(a1, *(const uint4*)&x[(size_t)r1 * 64 + 8 * i8]);
  if (v2 && g8 == 0) acc8(a2, *(const uint4*)&x[(size_t)r2 * 64 + 8 * i8]);
  if (v3 && g8 == 0) acc8(a3, *(const uint4*)&x[(size_t)r3 * 64 + 8 * i8]);

  // 32-wide main loop: 4 idx loads + 4 gathers per stream, 16 gathers in flight
  while ((c0 + 32 <= e0) | (c1 + 32 <= e1) | (c2 + 32 <= e2) | (c3 + 32 <= e3)) {
    const bool d0 = (c0 + 32 <= e0);
    const bool d1 = (c1 + 32 <= e1);
    const bool d2 = (c2 + 32 <= e2);
    const bool d3 = (c3 + 32 <= e3);
    int n0a=0,n0b=0,n0c=0,n0d=0, n1a=0,n1b=0,n1c=0,n1d=0;
    int n2a=0,n2b=0,n2c=0,n2d=0, n3a=0,n3b=0,n3c=0,n3d=0;
    if (d0) { n0a=idx[c0+g8]; n0b=idx[c0+8+g8]; n0c=idx[c0+16+g8]; n0d=idx[c0+24+g8]; }
    if (d1) { n1a=idx[c1+g8]; n1b=idx[c1+8+g8]; n1c=idx[c1+16+g8]; n1d=idx[c1+24+g8]; }
    if (d2) { n2a=idx[c2+g8]; n2b=idx[c2+8+g8]; n2c=idx[c2+16+g8]; n2d=idx[c2+24+g8]; }
    if (d3) { n3a=idx[c3+g8]; n3b=idx[c3+8+g8]; n3c=idx[c3+16+g8]; n3d=idx[c3+24+g8]; }
    uint4 u0a,u0b,u0c,u0d, u1a,u1b,u1c,u1d, u2a,u2b,u2c,u2d, u3a,u3b,u3c,u3d;
    if (d0) { u0a=*(const uint4*)&x[(size_t)n0a*64+8*i8]; u0b=*(const uint4*)&x[(size_t)n0b*64+8*i8];
              u0c=*(const uint4*)&x[(size_t)n0c*64+8*i8]; u0d=*(const uint4*)&x[(size_t)n0d*64+8*i8]; }
    if (d1) { u1a=*(const uint4*)&x[(size_t)n1a*64+8*i8]; u1b=*(const uint4*)&x[(size_t)n1b*64+8*i8];
              u1c=*(const uint4*)&x[(size_t)n1c*64+8*i8]; u1d=*(const uint4*)&x[(size_t)n1d*64+8*i8]; }
    if (d2) { u2a=*(const uint4*)&x[(size_t)n2a*64+8*i8]; u2b=*(const uint4*)&x[(size_t)n2b*64+8*i8];
              u2c=*(const uint4*)&x[(size_t)n2c*64+8*i8]; u2d=*(const uint4*)&x[(size_t)n2d*64+8*i8]; }
    if (d3) { u3a=*(const uint4*)&x[(size_t)n3a*64+8*i8]; u3b=*(const uint4*)&x[(size_t)n3b*64+8*i8];
              u3c=*(const uint4*)&x[(size_t)n3c*64+8*i8]; u3d=*(const uint4*)&x[(size_t)n3d*64+8*i8]; }
    if (d0) { acc8(a0,u0a); acc8(a0,u0b); acc8(a0,u0c); acc8(a0,u0d); c0 += 32; }
    if (d1) { acc8(a1,u1a); acc8(a1,u1b); acc8(a1,u1c); acc8(a1,u1d); c1 += 32; }
    if (d2) { acc8(a2,u2a); acc8(a2,u2b); acc8(a2,u2c); acc8(a2,u2d); c2 += 32; }
    if (d3) { acc8(a3,u3a); acc8(a3,u3b); acc8(a3,u3c); acc8(a3,u3d); c3 += 32; }
  }
  // 16-wide pass
  {
    const bool d0 = (c0 + 16 <= e0);
    const bool d1 = (c1 + 16 <= e1);
    const bool d2 = (c2 + 16 <= e2);
    const bool d3 = (c3 + 16 <= e3);
    int n0a=0,n0b=0, n1a=0,n1b=0, n2a=0,n2b=0, n3a=0,n3b=0;
    if (d0) { n0a = idx[c0 + g8]; n0b = idx[c0 + 8 + g8]; }
    if (d1) { n1a = idx[c1 + g8]; n1b = idx[c1 + 8 + g8]; }
    if (d2) { n2a = idx[c2 + g8]; n2b = idx[c2 + 8 + g8]; }
    if (d3) { n3a = idx[c3 + g8]; n3b = idx[c3 + 8 + g8]; }
    uint4 u0a,u0b,u1a,u1b,u2a,u2b,u3a,u3b;
    if (d0) { u0a=*(const uint4*)&x[(size_t)n0a*64+8*i8]; u0b=*(const uint4*)&x[(size_t)n0b*64+8*i8]; }
    if (d1) { u1a=*(const uint4*)&x[(size_t)n1a*64+8*i8]; u1b=*(const uint4*)&x[(size_t)n1b*64+8*i8]; }
    if (d2) { u2a=*(const uint4*)&x[(size_t)n2a*64+8*i8]; u2b=*(const uint4*)&x[(size_t)n2b*64+8*i8]; }
    if (d3) { u3a=*(const uint4*)&x[(size_t)n3a*64+8*i8]; u3b=*(const uint4*)&x[(size_t)n3b*64+8*i8]; }
    if (d0) { acc8(a0,u0a); acc8(a0,u0b); c0 += 16; }
    if (d1) { acc8(a1,u1a); acc8(a1,u1b); c1 += 16; }
    if (d2) { acc8(a2,u2a); acc8(a2,u2b); c2 += 16; }
    if (d3) { acc8(a3,u3a); acc8(a3,u3b); c3 += 16; }
  }
  // 8-wide pass
  {
    const bool d0 = (c0 + 8 <= e0);
    const bool d1 = (c1 + 8 <= e1);
    const bool d2 = (c2 + 8 <= e2);
    const bool d3 = (c3 + 8 <= e3);
    int n0 = 0, n1 = 0, n2 = 0, n3 = 0;
    if (d0) n0 = idx[c0 + g8];
    if (d1) n1 = idx[c1 + g8];
    if (d2) n2 = idx[c2 + g8];
    if (d3) n3 = idx[c3 + g8];
    uint4 u0, u1, u2, u3;
    if (d0) u0 = *(const uint4*)&x[(size_t)n0 * 64 + 8 * i8];
    if (d1) u1 = *(const uint4*)&x[(size_t)n1 * 64 + 8 * i8];
    if (d2) u2 = *(const uint4*)&x[(size_t)n2 * 64 + 8 * i8];
    if (d3) u3 = *(const uint4*)&x[(size_t)n3 * 64 + 8 * i8];
    if (d0) { acc8(a0, u0); c0 += 8; }
    if (d1) { acc8(a1, u1); c1 += 8; }
    if (d2) { acc8(a2, u2); c2 += 8; }
    if (d3) { acc8(a3, u3); c3 += 8; }
  }
  // remainder (< 8 per stream)
  {
    const int rem0 = e0 - c0;
    const int rem1 = e1 - c1;
    const int rem2 = e2 - c2;
    const int rem3 = e3 - c3;
    int n0 = 0, n1 = 0, n2 = 0, n3 = 0;
    if (g8 < rem0) n0 = idx[c0 + g8];
    if (g8 < rem1) n1 = idx[c1 + g8];
    if (g8 < rem2) n2 = idx[c2 + g8];
    if (g8 < rem3) n3 = idx[c3 + g8];
    uint4 u0, u1, u2, u3;
    if (g8 < rem0) u0 = *(const uint4*)&x[(size_t)n0 * 64 + 8 * i8];
    if (g8 < rem1) u1 = *(const uint4*)&x[(size_t)n1 * 64 + 8 * i8];
    if (g8 < rem2) u2 = *(const uint4*)&x[(size_t)n2 * 64 + 8 * i8];
    if (g8 < rem3) u3 = *(const uint4*)&x[(size_t)n3 * 64 + 8 * i8];
    if (g8 < rem0) acc8(a0, u0);
    if (g8 < rem1) acc8(a1, u1);
    if (g8 < rem2) acc8(a2, u2);
    if (g8 < rem3) acc8(a3, u3);
  }

  // fold neighbor-slot groups (g8) -> lanes 0..7 hold the row sums
#pragma unroll
  for (int k = 0; k < 8; ++k) {
#pragma unroll
    for (int o = 8; o <= 32; o <<= 1) {
      a0[k] += __shfl_xor(a0[k], o, 64);
      a1[k] += __shfl_xor(a1[k], o, 64);
      a2[k] += __shfl_xor(a2[k], o, 64);
      a3[k] += __shfl_xor(a3[k], o, 64);
    }
  }
  if (g8 == 0) {
    __half hv[8];
#pragma unroll
    for (int k = 0; k < 8; ++k) hv[k] = __float2half(a0[k]);
    *(uint4*)&AsH[w * 4 + 0][8 * i8] = *(uint4*)hv;
#pragma unroll
    for (int k = 0; k < 8; ++k) hv[k] = __float2half(a1[k]);
    *(uint4*)&AsH[w * 4 + 1][8 * i8] = *(uint4*)hv;
#pragma unroll
    for (int k = 0; k < 8; ++k) hv[k] = __float2half(a2[k]);
    *(uint4*)&AsH[w * 4 + 2][8 * i8] = *(uint4*)hv;
#pragma unroll
    for (int k = 0; k < 8; ++k) hv[k] = __float2half(a3[k]);
    *(uint4*)&AsH[w * 4 + 3][8 * i8] = *(uint4*)hv;
  }
  __syncthreads();

  // ---- MFMA phase: wave w computes rows 0..15 x cols [16w, 16w+16) ----
  v4f acc = (v4f){0.f, 0.f, 0.f, 0.f};
#pragma unroll
  for (int hh = 0; hh < 2; ++hh) {
    v8h af = *(const v8h*)&AsH[i][hh * 32 + q * 8];
    v8h bf = *(const v8h*)&BT[(size_t)(w * 16 + i) * 64 + hh * 32 + q * 8];
    acc = __builtin_amdgcn_mfma_f32_16x16x32_f16(af, bf, acc, 0, 0, 0);
  }

  const int col = w * 16 + i;
  float s = 0.f, qq = 0.f;
#pragma unroll
  for (int j = 0; j < 4; ++j) {
    int row = rblk + 4 * q + j;
    if (row >= M) continue;
    float v = h2f(fmaxf(acc[j] + bias[col], 0.f));
    h[(size_t)row * 64 + col] = __float2half(v);
    s += v;
    qq += v * v;
  }
  s  += __shfl_xor(s, 16, 64);  qq += __shfl_xor(qq, 16, 64);
  s  += __shfl_xor(s, 32, 64);  qq += __shfl_xor(qq, 32, 64);
  if (q == 0) {
    const int bkt = (blockIdx.x & (NBUCKET - 1)) * 128;
    atomicAdd(&gstatP[bkt + col], s);
    atomicAdd(&gstatP[bkt + 64 + col], qq);
  }
}

// ---------------------------------------------------------------------------
// K2 (64-row tile, MFMA): Xout = relu(BN(h) @ W2 + b2), col63 = 0.
// Prologue reduces the NBUCKET BN-stat buckets. Optional fused zchain
// epilogue (last layer).
// ---------------------------------------------------------------------------
__global__ __launch_bounds__(256) void k_layer2(
    const __half* __restrict__ A, const __half* __restrict__ BT,
    const float* __restrict__ bias,
    const float* __restrict__ gstat, const float* __restrict__ gamma,
    const float* __restrict__ beta,
    __half* __restrict__ Xout, int M,
    const __half* __restrict__ Z0, const __half* __restrict__ Z1,
    const __half* __restrict__ Z2, __half* __restrict__ Xh, int doZ)
{
  __shared__ float scl_s[64], shf_s[64];
  __shared__ float tmp[128];
  const int tid  = threadIdx.x;
  const int w    = tid >> 6;
  const int lane = tid & 63;
  const int q    = lane >> 4;
  const int i    = lane & 15;
  const int rblk = blockIdx.x * 64;
  const int arow = rblk + w * 16 + i;

  if (tid < 128) {
    float a = 0.f;
#pragma unroll
    for (int b2 = 0; b2 < NBUCKET; ++b2) a += gstat[b2 * 128 + tid];
    tmp[tid] = a;
  }
  __syncthreads();
  if (tid < 64) {
    float mu  = tmp[tid] / (float)M;
    float var = tmp[64 + tid] / (float)M - mu * mu;
    float sv  = gamma[tid] / sqrtf(var + BN_EPS_F);
    scl_s[tid] = sv;
    shf_s[tid] = beta[tid] - mu * sv;
  }
  __syncthreads();

  v4f acc[4];
#pragma unroll
  for (int t = 0; t < 4; ++t) acc[t] = (v4f){0.f, 0.f, 0.f, 0.f};
#pragma unroll
  for (int hh = 0; hh < 2; ++hh) {
    const int k0 = hh * 32 + q * 8;
    v8h af = (v8h){0, 0, 0, 0, 0, 0, 0, 0};
    {
      float hv[8] = {0,0,0,0,0,0,0,0};
      if (arow < M) {
        uint4 u = *(const uint4*)&A[(size_t)arow * 64 + k0];
        __half2 h0 = *(__half2*)&u.x;
        __half2 h1 = *(__half2*)&u.y;
        __half2 h2 = *(__half2*)&u.z;
        __half2 h3 = *(__half2*)&u.w;
        hv[0] = __low2float(h0); hv[1] = __high2float(h0);
        hv[2] = __low2float(h1); hv[3] = __high2float(h1);
        hv[4] = __low2float(h2); hv[5] = __high2float(h2);
        hv[6] = __low2float(h3); hv[7] = __high2float(h3);
      }
#pragma unroll
      for (int k = 0; k < 8; ++k)
        af[k] = (_Float16)fmaf(hv[k], scl_s[k0 + k], shf_s[k0 + k]);
    }
#pragma unroll
    for (int t = 0; t < 4; ++t) {
      v8h bf = *(const v8h*)&BT[(size_t)(t * 16 + i) * 64 + k0];
      acc[t] = __builtin_amdgcn_mfma_f32_16x16x32_f16(af, bf, acc[t], 0, 0, 0);
    }
  }

#pragma unroll
  for (int j = 0; j < 4; ++j) {
    int row = rblk + w * 16 + 4 * q + j;
    if (row >= M) continue;
#pragma unroll
    for (int t = 0; t < 4; ++t) {
      float v = fmaxf(acc[t][j] + bias[i + 16 * t], 0.f);
      if (i == 15 && t == 3) v = 0.f;   // col 63
      Xout[(size_t)row * 64 + i + 16 * t] = __float2half(v);
    }
  }

  if (doZ) {
    __syncthreads();                     // all rows of this block written
    const int g16  = tid >> 4;           // 16 groups of 16 lanes
    const int il   = tid & 15;
#pragma unroll
    for (int p = 0; p < 4; ++p) {
      int row = rblk + p * 16 + g16;
      zchain_row(row, il, row < M, Z0, Z1, Z2, Xout, Xh);
    }
  }
}

// ---------------------------------------------------------------------------
// Per-graph pooling (from Xh fp16, rows gstart[g]..gstart[g+1]) + MLP head
// ---------------------------------------------------------------------------
__global__ __launch_bounds__(128) void k_mlp(const __half* __restrict__ Xh,
                                             const int* __restrict__ gstart,
                                             const float* __restrict__ fc1W, const float* __restrict__ fc1b,
                                             const float* __restrict__ fc2W, const float* __restrict__ fc2b,
                                             const float* __restrict__ fc3W, const float* __restrict__ fc3b,
                                             float* __restrict__ out) {
  __shared__ float p2s[2][64];
  __shared__ float p[64], o1[128], o2[64], lg[10], red[2];
  int g = blockIdx.x, t = threadIdx.x;
  int beg = gstart[g], end = gstart[g + 1];
  {
    int half = t >> 6, c = t & 63;
    float a = 0.f;
    int r = beg + half;
    for (; r + 6 <= end; r += 8) {
      float v0 = __half2float(Xh[(size_t)(r + 0) * 64 + c]);
      float v1 = __half2float(Xh[(size_t)(r + 2) * 64 + c]);
      float v2 = __half2float(Xh[(size_t)(r + 4) * 64 + c]);
      float v3 = __half2float(Xh[(size_t)(r + 6) * 64 + c]);
      a += (v0 + v1) + (v2 + v3);
    }
    for (; r < end; r += 2) a += __half2float(Xh[(size_t)r * 64 + c]);
    p2s[half][c] = a;
  }
  __syncthreads();
  if (t < 64) p[t] = p2s[0][t] + p2s[1][t];
  __syncthreads();
  {
    float a = fc1b[t];
    for (int k = 0; k < 64; ++k) a = fmaf(p[k], fc1W[k * 128 + t], a);
    o1[t] = fmaxf(a, 0.f);
  }
  __syncthreads();
  if (t < 64) {
    float a = fc2b[t];
    for (int k = 0; k < 128; ++k) a = fmaf(o1[k], fc2W[k * 64 + t], a);
    o2[t] = fmaxf(a, 0.f);
  }
  __syncthreads();
  if (t < 10) {
    float a = fc3b[t];
    for (int k = 0; k < 64; ++k) a = fmaf(o2[k], fc3W[k * 10 + t], a);
    lg[t] = a;
  }
  __syncthreads();
  if (t == 0) {
    float mx = lg[0];
    for (int j = 1; j < 10; ++j) mx = fmaxf(mx, lg[j]);
    float s = 0.f;
    for (int j = 0; j < 10; ++j) s += expf(lg[j] - mx);
    red[0] = mx;
    red[1] = logf(s);
  }
  __syncthreads();
  if (t < 10) out[(size_t)g * 10 + t] = lg[t] - red[0] - red[1];
}

// ---------------------------------------------------------------------------
extern "C" void kernel_launch(void* const* d_in, const int* in_sizes, int n_in,
                              void* d_out, int out_size, void* d_ws, size_t ws_size,
                              hipStream_t stream) {
  const float* x_in  = (const float*)d_in[0];
  const int*   ei    = (const int*)d_in[1];
  const int*   batch = (const int*)d_in[2];
  const float* W0    = (const float*)d_in[3];
  const float* b0    = (const float*)d_in[4];
  const float* cW1   = (const float*)d_in[5];
  const float* cb1   = (const float*)d_in[6];
  const float* gamma = (const float*)d_in[7];
  const float* beta  = (const float*)d_in[8];
  const float* cW2   = (const float*)d_in[9];
  const float* cb2   = (const float*)d_in[10];
  const float* fc1W  = (const float*)d_in[11];
  const float* fc1b  = (const float*)d_in[12];
  const float* fc2W  = (const float*)d_in[13];
  const float* fc2b  = (const float*)d_in[14];
  const float* fc3W  = (const float*)d_in[15];
  const float* fc3b  = (const float*)d_in[16];
  float* out = (float*)d_out;

  const int N = in_sizes[0] / 128;
  const int E = in_sizes[1] / 2;
  const int L = in_sizes[5] / (64 * 64);
  const int G = out_size / 10;
  const int* src = ei;
  const int* dst = ei + E;

  char* ws = (char*)d_ws;
  size_t off = 0;
  auto alloc = [&](size_t bytes) -> char* {
    char* p = ws + off;
    off += (bytes + 255) & ~(size_t)255;
    return p;
  };
  __half* X0  = (__half*)alloc((size_t)N * 64 * 2);
  __half* X0L = (__half*)alloc((size_t)N * 64 * 2);   // laundered X0
  __half* X1  = (__half*)alloc((size_t)N * 64 * 2);
  __half* X2  = (__half*)alloc((size_t)N * 64 * 2);
  __half* X3  = (__half*)alloc((size_t)N * 64 * 2);
  __half* Bf  = (__half*)alloc((size_t)N * 64 * 2);
  __half* Xh  = (__half*)alloc((size_t)N * 64 * 2);
  __half* W0T = (__half*)alloc((size_t)64 * 128 * 2);
  __half* W1T = (__half*)alloc((size_t)L * 64 * 64 * 2);
  __half* W2T = (__half*)alloc((size_t)L * 64 * 64 * 2);
  int*    gstart = (int*)alloc((size_t)(G + 1) * 4);
  // ---- zeroed region: cnt, gstatAll, ovf (contiguous, zeroed by k_zero) ----
  int*   cnt  = (int*)alloc((size_t)N * 4);
  float* gstatAll = (float*)alloc((size_t)3 * NBUCKET * 128 * 4);
  int*   ovf  = (int*)alloc(256);        // one flag (padded)
  char*  zero_end = ws + off;
  // -------------------------------------------------------------------------
  int*   cnt2 = (int*)alloc((size_t)N * 4);           // laundered cnt
  unsigned short* slots  = (unsigned short*)alloc((size_t)N * CAP * 2);
  unsigned short* slots2 = (unsigned short*)alloc((size_t)N * CAP * 2);
  int*   rowptr = (int*)alloc((size_t)(N + 1) * 4);
  int*   cursor = (int*)alloc((size_t)N * 4);
  unsigned short* csr = (unsigned short*)alloc((size_t)E * 2);
  int*   bsum   = (int*)alloc(256 * 4);
  int*   boff   = (int*)alloc(256 * 4);
  __half* Xs[4] = {X0L, X1, X2, X3};     // downstream consumers use laundered X0

  const int zwords = (int)((zero_end - (char*)cnt) / 4);

  const int mmGrid    = (N + 63) / 64;
  const int l1Grid    = (N + 15) / 16;
  const int edge4Grid = (E / 4 + 255) / 256 + 1;
  const int fillGrid  = edge4Grid * 8;                // 8 XCD replicas
  const int gbGrid    = (N + 255) / 256;
  const int wBlk      = (L * 4096 + 255) / 256;
  const int nS16      = N * CAP * 2 / 16;             // uint4 count: slots
  const int nX16      = N * 64 * 2 / 16;              // uint4 count: X0
  const int nC16      = (N * 4 + 15) / 16;            // uint4 count: cnt
  const int packGrid  = (nS16 + nX16 + nC16 + 255) / 256;

  // zero cnt/gstat/ovf + convert W0T (needed by k_front's mm0 section)
  k_zero<<<256, 256, 0, stream>>>(W0, W0T, cnt, zwords);

  // fused front-end: XCD-partitioned slot-fill | mm0 | gb | W1T/W2T cvt
  k_front<<<fillGrid + mmGrid + gbGrid + wBlk, 256, 0, stream>>>(
      x_in, W0T, b0, X0, N,
      src, dst, E, cnt, slots, ovf,
      batch, G, gstart,
      cW1, cW2, L, W1T, W2T,
      fillGrid, mmGrid, gbGrid);

  // launder everything the first layer1 touches: slots, X0, cnt
  k_pack3<<<packGrid, 256, 0, stream>>>(
      (const uint4*)slots, (uint4*)slots2, nS16,
      (const uint4*)X0,    (uint4*)X0L,    nX16,
      (const uint4*)cnt,   (uint4*)cnt2,   nC16);

  // overflow fallback chain (early-exit when ovf == 0)
  const int NB = (N + 255) / 256;
  k_scan1<<<NB, 256, 0, stream>>>(ovf, cnt, N, rowptr, bsum);
  k_scan2<<<1, 256, 0, stream>>>(ovf, bsum, NB, boff);
  k_scan3<<<NB, 256, 0, stream>>>(ovf, rowptr, boff, cursor, N, E);
  k_fill<<<edge4Grid, 256, 0, stream>>>(ovf, src, dst, E, cursor, csr);

  for (int i = 0; i < L; ++i) {
    float* gstat = gstatAll + (size_t)i * NBUCKET * 128;
    const int doZ = (i == L - 1) ? 1 : 0;
    k_layer1<<<l1Grid, 256, 0, stream>>>(Xs[i], ovf, cnt2, slots2, rowptr, csr,
                                         W1T + (size_t)i * 4096, cb1 + i * 64,
                                         Bf, gstat, N);
    k_layer2<<<mmGrid, 256, 0, stream>>>(Bf, W2T + (size_t)i * 4096, cb2 + i * 64,
                                         gstat, gamma + i * 64, beta + i * 64,
                                         Xs[i + 1], N,
                                         Xs[0], X1, X2, Xh, doZ);
  }

  k_mlp<<<G, 128, 0, stream>>>(Xh, gstart, fc1W, fc1b, fc2W, fc2b, fc3W, fc3b, out);
}

// Round 12
// 338.326 us; speedup vs baseline: 1.0433x; 1.0032x over previous
//
#include <hip/hip_runtime.h>
#include <hip/hip_fp16.h>
#include <math.h>

#define SCALING_F 0.46211715726000974f   // tanh(0.5)
#define MAXNORM_F 0.996f                 // 1 - BALL_EPS
#define MINNORM_F 1e-15f
#define BN_EPS_F  1e-5f

#define NBUCKET 32                       // BN-stat atomic spread buckets
#define CAP     64                       // slot capacity per node (mean deg 16)

typedef _Float16 v8h __attribute__((ext_vector_type(8)));
typedef float    v4f __attribute__((ext_vector_type(4)));

// reduce over the 16-lane group holding one row
__device__ __forceinline__ float rsum16(float v) {
  v += __shfl_xor(v, 1, 64);
  v += __shfl_xor(v, 2, 64);
  v += __shfl_xor(v, 4, 64);
  v += __shfl_xor(v, 8, 64);
  return v;
}

__device__ __forceinline__ void rsum16x6(float& a, float& b, float& c,
                                         float& d, float& e, float& f) {
#pragma unroll
  for (int o = 1; o <= 8; o <<= 1) {
    a += __shfl_xor(a, o, 64);
    b += __shfl_xor(b, o, 64);
    c += __shfl_xor(c, o, 64);
    d += __shfl_xor(d, o, 64);
    e += __shfl_xor(e, o, 64);
    f += __shfl_xor(f, o, 64);
  }
}

__device__ __forceinline__ float h2f(float v) {   // fp16 round-trip
  return __half2float(__float2half(v));
}

// accumulate 8 halfs (as uint4) into float[8]
__device__ __forceinline__ void acc8(float* a, uint4 u) {
  __half2 h0 = *(__half2*)&u.x;
  __half2 h1 = *(__half2*)&u.y;
  __half2 h2 = *(__half2*)&u.z;
  __half2 h3 = *(__half2*)&u.w;
  a[0] += __low2float(h0); a[1] += __high2float(h0);
  a[2] += __low2float(h1); a[3] += __high2float(h1);
  a[4] += __low2float(h2); a[5] += __high2float(h2);
  a[6] += __low2float(h3); a[7] += __high2float(h3);
}

// load 4 halfs (8B) -> float[4]
__device__ __forceinline__ void load4f(const __half* p, float* a) {
  uint2 u = *(const uint2*)p;
  __half2 h0 = *(__half2*)&u.x;
  __half2 h1 = *(__half2*)&u.y;
  a[0] = __low2float(h0); a[1] = __high2float(h0);
  a[2] = __low2float(h1); a[3] = __high2float(h1);
}

// ---------------------------------------------------------------------------
// zchain body (fused epilogue): per row, hyperbolic recurrence.
// ---------------------------------------------------------------------------
__device__ __forceinline__ void zchain_row(
    int row, int i, bool valid,
    const __half* __restrict__ X0, const __half* __restrict__ X1,
    const __half* __restrict__ X2, const __half* __restrict__ X3,
    __half* __restrict__ Xh)
{
  float x0[4] = {0,0,0,0}, x1[4] = {0,0,0,0}, x2[4] = {0,0,0,0}, x3[4] = {0,0,0,0};
  if (valid) {
    load4f(&X0[(size_t)row * 64 + 4 * i], x0);
    load4f(&X1[(size_t)row * 64 + 4 * i], x1);
    load4f(&X2[(size_t)row * 64 + 4 * i], x2);
    load4f(&X3[(size_t)row * 64 + 4 * i], x3);
  }

  float zc[4], zp[4] = {0.f, 0.f, 0.f, 0.f};
  {
    float sx = rsum16(x0[0]*x0[0] + x0[1]*x0[1] + x0[2]*x0[2] + x0[3]*x0[3]);
    float norm = fmaxf(sqrtf(sx), MINNORM_F);
    float s = ((norm > MAXNORM_F) ? (MAXNORM_F / norm) : 1.0f) * SCALING_F;
#pragma unroll
    for (int e = 0; e < 4; ++e) zc[e] = x0[e] * s;
  }

  const float* Xi[3] = {x1, x2, x3};
#pragma unroll
  for (int li = 0; li < 3; ++li) {
    const float* xv = Xi[li];

    float p1 = xv[0]*xv[0] + xv[1]*xv[1] + xv[2]*xv[2] + xv[3]*xv[3];
    float p2 = zc[0]*zc[0]+zc[1]*zc[1]+zc[2]*zc[2]+zc[3]*zc[3];
    float p3 = zp[0]*zp[0]+zp[1]*zp[1]+zp[2]*zp[2]+zp[3]*zp[3];
    float p4 = zp[0]*zc[0]+zp[1]*zc[1]+zp[2]*zc[2]+zp[3]*zc[3];
    float p5 = zp[0]*xv[0]+zp[1]*xv[1]+zp[2]*xv[2]+zp[3]*xv[3];
    float p6 = zc[0]*xv[0]+zc[1]*xv[1]+zc[2]*xv[2]+zc[3]*xv[3];
    rsum16x6(p1, p2, p3, p4, p5, p6);
    float zc63 = __shfl(zc[3], 15, 16);   // col 63 = lane 15, elem 3
    float zp63 = __shfl(zp[3], 15, 16);

    float nzc2 = fmaxf(p2, MINNORM_F);
    float icz  = 1.0f / nzc2;
    float na2  = p2 * icz * icz;
    float r2   = na2 - 1.0f;
    float a63  = zc63 * icz;

    float sxn = fmaxf(sqrtf(p1), MINNORM_F);
    float sc  = ((sxn > MAXNORM_F) ? (MAXNORM_F / sxn) : 1.0f) * SCALING_F;
    float Sch2   = sc * sc * p1;         // Σch² (ch63 = 0: col63 zeroed in X)
    float Szp_a  = p4 * icz;
    float Sa_ch  = sc * p6 * icz;
    float Szp_ch = sc * p5;
    float Su_a   = Szp_a - na2;
    float Su2    = p3 - 2.0f * Szp_a + na2;
    float nu2    = fmaxf(Su2, MINNORM_F);
    float t1     = r2 / nu2;
    float Szp22  = fmaxf(t1*t1*Su2 + 2.0f*t1*Su_a + na2, 0.0f);
    float npn    = fmaxf(sqrtf(Szp22), MINNORM_F);
    float ipn    = 1.0f / npn;
    float zp2_63 = t1 * (zp63 - a63) + a63;
    float Szp2ch = t1 * (Szp_ch - Sa_ch) + Sa_ch;
    float rdc    = -ipn * Szp2ch;
    float rdr    = 1.0f - 2.0f*ipn*zp2_63 + ipn*ipn*Szp22;
    float m2     = 2.0f * rdc / rdr;
    float Szp2a  = t1 * Su_a + na2;
    float Srr_a  = a63 - ipn * Szp2a;
    float Sc2a   = Sa_ch - m2 * Srr_a;
    float Sc22   = Sch2 - 2.0f*m2*rdc + m2*m2*rdr;
    float Sc2ma  = Sc22 - 2.0f*Sc2a + na2;
    float nu22   = fmaxf(Sc2ma, MINNORM_F);
    float t2     = r2 / nu22;

    float zn[4];
#pragma unroll
    for (int e = 0; e < 4; ++e) {
      float ai  = zc[e] * icz;
      float zp2 = t1 * (zp[e] - ai) + ai;
      float rri = ((i == 15 && e == 3) ? 1.0f : 0.0f) - ipn * zp2;
      float c2  = sc * xv[e] - m2 * rri;
      zn[e]     = t2 * (c2 - ai) + ai;
    }
#pragma unroll
    for (int e = 0; e < 4; ++e) { zp[e] = zc[e]; zc[e] = zn[e]; }
  }

  {
    float sz = rsum16(zc[0]*zc[0] + zc[1]*zc[1] + zc[2]*zc[2] + zc[3]*zc[3]);
    float yn  = fmaxf(sqrtf(sz), MINNORM_F);
    float t   = fminf(yn, 1.0f);
    float ath = 0.5f * logf((1.0f + t) / (1.0f - t));
    float wsc = ath / yn;
    if (valid) {
      __half hv[4];
      hv[0] = __float2half(zc[0] * wsc);
      hv[1] = __float2half(zc[1] * wsc);
      hv[2] = __float2half(zc[2] * wsc);
      hv[3] = __float2half(zc[3] * wsc);
      *(uint2*)&Xh[(size_t)row * 64 + 4 * i] = *(uint2*)hv;
    }
  }
}

// ---------------------------------------------------------------------------
// k_zero: zero cnt/gstat/ovf region + convert W0T (needed by k_front's mm0).
// ---------------------------------------------------------------------------
__global__ __launch_bounds__(256) void k_zero(
    const float* __restrict__ W0, __half* __restrict__ W0T,
    int* __restrict__ zbase, int zwords)
{
  int id = blockIdx.x * 256 + threadIdx.x;
  if (id < 64 * 128) {            // W0T[n][k], k<128
    int n = id >> 7, k = id & 127;
    W0T[id] = __float2half(W0[(size_t)k * 64 + n]);
  }
  const int stride = gridDim.x * 256;
  for (int z = id; z < zwords; z += stride) zbase[z] = 0;
}

// ---------------------------------------------------------------------------
// Fused front-end: [0,DBLK) XCD-partitioned slot-fill | [,+MBLK) mm0 |
// [,+GBLK) graph bounds | rest: W1T/W2T conversion.
// Slot-fill replicated 8x: block bx -> xcd = bx&7, chunk = bx>>3; handles
// only dst in slice [xcd*per,(xcd+1)*per) so each slots/cnt slice is written
// from one XCD (scatter stays L2-local; R10: WRITE 51->36MB, dur 76->56us).
// per is a multiple of 128 rows so layer1's swizzle can align reader XCD
// with writer XCD. Mapping is a locality heuristic; correctness-independent.
// ---------------------------------------------------------------------------
__global__ __launch_bounds__(256) void k_front(
    const float* __restrict__ A, const __half* __restrict__ BT,
    const float* __restrict__ bias, __half* __restrict__ X, int M,
    const int* __restrict__ src, const int* __restrict__ dst, int E,
    int* __restrict__ cnt, unsigned short* __restrict__ slots,
    int* __restrict__ ovf,
    const int* __restrict__ batch, int G, int* __restrict__ gstart,
    const float* __restrict__ cW1, const float* __restrict__ cW2, int L,
    __half* __restrict__ W1T, __half* __restrict__ W2T,
    int per, int DBLK, int MBLK, int GBLK)
{
  int bx = blockIdx.x;
  const int tid = threadIdx.x;

  if (bx < DBLK) {                       // ---- XCD-partitioned slot-fill ----
    const int xcd   = bx & 7;
    const int chunk = bx >> 3;
    const int lo    = xcd * per;
    const int hi    = (lo + per < M) ? (lo + per) : M;
    int i0 = (chunk * 256 + tid) * 4;
    if (i0 + 4 <= E) {
      int4 d = *(const int4*)&dst[i0];
      int4 s = *(const int4*)&src[i0];
      if (d.x >= lo && d.x < hi) {
        int p = atomicAdd(&cnt[d.x], 1);
        if (p < CAP) slots[(size_t)d.x * CAP + p] = (unsigned short)s.x; else *ovf = 1;
      }
      if (d.y >= lo && d.y < hi) {
        int p = atomicAdd(&cnt[d.y], 1);
        if (p < CAP) slots[(size_t)d.y * CAP + p] = (unsigned short)s.y; else *ovf = 1;
      }
      if (d.z >= lo && d.z < hi) {
        int p = atomicAdd(&cnt[d.z], 1);
        if (p < CAP) slots[(size_t)d.z * CAP + p] = (unsigned short)s.z; else *ovf = 1;
      }
      if (d.w >= lo && d.w < hi) {
        int p = atomicAdd(&cnt[d.w], 1);
        if (p < CAP) slots[(size_t)d.w * CAP + p] = (unsigned short)s.w; else *ovf = 1;
      }
    } else {
      for (int i = i0; i < E; ++i) {
        int dv = dst[i];
        if (dv >= lo && dv < hi) {
          int p = atomicAdd(&cnt[dv], 1);
          if (p < CAP) slots[(size_t)dv * CAP + p] = (unsigned short)src[i];
          else *ovf = 1;
        }
      }
    }
    return;
  }
  bx -= DBLK;

  if (bx < MBLK) {                       // ---- mm0 ----
    const int w    = tid >> 6;
    const int lane = tid & 63;
    const int q    = lane >> 4;
    const int i    = lane & 15;
    const int rblk = bx * 64;
    const int arow = rblk + w * 16 + i;

    v4f acc[4];
#pragma unroll
    for (int t = 0; t < 4; ++t) acc[t] = (v4f){0.f, 0.f, 0.f, 0.f};

#pragma unroll
    for (int hh = 0; hh < 4; ++hh) {
      v8h af = (v8h){0, 0, 0, 0, 0, 0, 0, 0};
      if (arow < M) {
        const float* p = &A[(size_t)arow * 128 + hh * 32 + q * 8];
        float4 fa = *(const float4*)p;
        float4 fb = *(const float4*)(p + 4);
        af[0] = (_Float16)fa.x; af[1] = (_Float16)fa.y;
        af[2] = (_Float16)fa.z; af[3] = (_Float16)fa.w;
        af[4] = (_Float16)fb.x; af[5] = (_Float16)fb.y;
        af[6] = (_Float16)fb.z; af[7] = (_Float16)fb.w;
      }
#pragma unroll
      for (int t = 0; t < 4; ++t) {
        v8h bf = *(const v8h*)&BT[(size_t)(t * 16 + i) * 128 + hh * 32 + q * 8];
        acc[t] = __builtin_amdgcn_mfma_f32_16x16x32_f16(af, bf, acc[t], 0, 0, 0);
      }
    }

#pragma unroll
    for (int j = 0; j < 4; ++j) {
      int row = rblk + w * 16 + 4 * q + j;
      if (row >= M) continue;
#pragma unroll
      for (int t = 0; t < 4; ++t)
        X[(size_t)row * 64 + i + 16 * t] =
            __float2half(fmaxf(acc[t][j] + bias[i + 16 * t], 0.f));
    }
    return;
  }
  bx -= MBLK;

  if (bx < GBLK) {                       // ---- graph boundaries ----
    int r = bx * 256 + tid;
    if (r >= M) return;
    int b = batch[r];
    int prev = (r == 0) ? -1 : batch[r - 1];
    for (int g = prev + 1; g <= b; ++g) gstart[g] = r;
    if (r == M - 1)
      for (int g = b + 1; g <= G; ++g) gstart[g] = M;
    return;
  }
  bx -= GBLK;

  {                                      // ---- W1T/W2T conversion ----
    int id = bx * 256 + tid;
    if (id < L * 64 * 64) {
      int l = id >> 12, rem = id & 4095;
      int n = rem >> 6, k = rem & 63;
      W1T[id] = __float2half(cW1[(size_t)l * 4096 + k * 64 + n]);
      W2T[id] = __float2half(cW2[(size_t)l * 4096 + k * 64 + n]);
    }
  }
}

// ---------------------------------------------------------------------------
// Launder pass: X0 only (slots/cnt now read XCD-locally by swizzled layer1).
// Streams the mm0-scattered X0 into a clean buffer with full-line traffic.
// ---------------------------------------------------------------------------
__global__ __launch_bounds__(256) void k_pack(
    const uint4* __restrict__ in, uint4* __restrict__ out, int n16)
{
  int i = blockIdx.x * 256 + threadIdx.x;
  if (i < n16) out[i] = in[i];
}

// ---------------------------------------------------------------------------
// Overflow-fallback CSR build (early-exit when no slot overflowed).
// ---------------------------------------------------------------------------
__global__ __launch_bounds__(256) void k_scan1(const int* __restrict__ ovf,
                                               const int* __restrict__ deg, int N,
                                               int* rowptr, int* bsum) {
  if (*ovf == 0) return;
  __shared__ int s[256];
  int t = threadIdx.x;
  int i = blockIdx.x * 256 + t;
  int v = (i < N) ? deg[i] : 0;
  s[t] = v;
  __syncthreads();
  for (int d = 1; d < 256; d <<= 1) {
    int add = (t >= d) ? s[t - d] : 0;
    __syncthreads();
    s[t] += add;
    __syncthreads();
  }
  if (i < N) rowptr[i] = s[t] - v;
  if (t == 255) bsum[blockIdx.x] = s[255];
}

__global__ __launch_bounds__(256) void k_scan2(const int* __restrict__ ovf,
                                               const int* __restrict__ bsum, int NB, int* boff) {
  if (*ovf == 0) return;
  __shared__ int s[256];
  int t = threadIdx.x;
  int v = (t < NB) ? bsum[t] : 0;
  s[t] = v;
  __syncthreads();
  for (int d = 1; d < 256; d <<= 1) {
    int add = (t >= d) ? s[t - d] : 0;
    __syncthreads();
    s[t] += add;
    __syncthreads();
  }
  boff[t] = s[t] - v;
}

__global__ __launch_bounds__(256) void k_scan3(const int* __restrict__ ovf,
                                               int* rowptr, const int* __restrict__ boff,
                                               int* cursor, int N, int E) {
  if (*ovf == 0) return;
  int i = blockIdx.x * 256 + threadIdx.x;
  if (i < N) {
    int v = rowptr[i] + boff[blockIdx.x];
    rowptr[i] = v;
    cursor[i] = v;
  }
  if (i == 0) rowptr[N] = E;
}

__global__ __launch_bounds__(256) void k_fill(const int* __restrict__ ovf,
                                              const int* __restrict__ src,
                                              const int* __restrict__ dst, int E,
                                              int* cursor, unsigned short* __restrict__ csr) {
  if (*ovf == 0) return;
  int i0 = (blockIdx.x * 256 + threadIdx.x) * 4;
  if (i0 + 4 <= E) {
    int4 d = *(const int4*)&dst[i0];
    int4 s = *(const int4*)&src[i0];
    int p0 = atomicAdd(&cursor[d.x], 1);
    int p1 = atomicAdd(&cursor[d.y], 1);
    int p2 = atomicAdd(&cursor[d.z], 1);
    int p3 = atomicAdd(&cursor[d.w], 1);
    csr[p0] = (unsigned short)s.x;
    csr[p1] = (unsigned short)s.y;
    csr[p2] = (unsigned short)s.z;
    csr[p3] = (unsigned short)s.w;
  } else {
    for (int i = i0; i < E; ++i) {
      int p = atomicAdd(&cursor[dst[i]], 1);
      csr[p] = (unsigned short)src[i];
    }
  }
}

// ---------------------------------------------------------------------------
// K1 (16-row tile, MFMA): h = relu((x[r] + sum_nb x[nb]) @ W1 + b1).
// Cooperative gather (8 slot-groups each take a DIFFERENT neighbor/round;
// staged 32/16/8-wide). Row-block SWIZZLE: block b (XCD b&7 under round-
// robin dispatch) processes row-blocks in slice b&7 — the slots/cnt lines it
// reads were written by its own XCD's slot-fill (L2-hit, no migration).
// Fast path reads fixed-stride slots; fallback (ovf) walks classic CSR.
// ---------------------------------------------------------------------------
__global__ __launch_bounds__(256, 4) void k_layer1(
    const __half* __restrict__ x,
    const int* __restrict__ ovf, const int* __restrict__ cnt,
    const unsigned short* __restrict__ slots,
    const int* __restrict__ rowptr, const unsigned short* __restrict__ csr,
    const __half* __restrict__ BT,
    const float* __restrict__ bias, __half* __restrict__ h,
    float* __restrict__ gstatP, int perBlk, int M)
{
  __shared__ __half AsH[16][80];   // 160B rows (16B aligned)
  const int tid  = threadIdx.x;
  const int w    = tid >> 6;
  const int lane = tid & 63;
  const int q    = lane >> 4;
  const int i    = lane & 15;
  const int g8   = lane >> 3;      // neighbor slot 0..7
  const int i8   = lane & 7;       // col group: cols 8*i8 .. +8
  // swizzle: XCD (b&7) owns slice (b&7); chunk index walks within the slice
  const int rblk = (((blockIdx.x & 7) * perBlk) + (blockIdx.x >> 3)) * 16;

  const int r0 = rblk + w * 4 + 0;
  const int r1 = rblk + w * 4 + 1;
  const int r2 = rblk + w * 4 + 2;
  const int r3 = rblk + w * 4 + 3;
  const bool v0 = (r0 < M), v1 = (r1 < M), v2 = (r2 < M), v3 = (r3 < M);

  float a0[8] = {0.f,0.f,0.f,0.f,0.f,0.f,0.f,0.f};
  float a1[8] = {0.f,0.f,0.f,0.f,0.f,0.f,0.f,0.f};
  float a2[8] = {0.f,0.f,0.f,0.f,0.f,0.f,0.f,0.f};
  float a3[8] = {0.f,0.f,0.f,0.f,0.f,0.f,0.f,0.f};

  const unsigned short* idx;
  int c0 = 0, e0 = 0, c1 = 0, e1 = 0, c2 = 0, e2 = 0, c3 = 0, e3 = 0;
  if (*ovf == 0) {                       // slot fast path
    idx = slots;
    if (v0) { c0 = r0 * CAP; e0 = c0 + cnt[r0]; }
    if (v1) { c1 = r1 * CAP; e1 = c1 + cnt[r1]; }
    if (v2) { c2 = r2 * CAP; e2 = c2 + cnt[r2]; }
    if (v3) { c3 = r3 * CAP; e3 = c3 + cnt[r3]; }
  } else {                               // CSR fallback
    idx = csr;
    if (v0) { c0 = rowptr[r0]; e0 = rowptr[r0 + 1]; }
    if (v1) { c1 = rowptr[r1]; e1 = rowptr[r1 + 1]; }
    if (v2) { c2 = rowptr[r2]; e2 = rowptr[r2 + 1]; }
    if (v3) { c3 = rowptr[r3]; e3 = rowptr[r3 + 1]; }
  }

  if (v0 && g8 == 0) acc8(a0, *(const uint4*)&x[(size_t)r0 * 64 + 8 * i8]);
  if (v1 && g8 == 0) acc8(a1, *(const uint4*)&x[(size_t)r1 * 64 + 8 * i8]);
  if (v2 && g8 == 0) acc8(a2, *(const uint4*)&x[(size_t)r2 * 64 + 8 * i8]);
  if (v3 && g8 == 0) acc8(a3, *(const uint4*)&x[(size_t)r3 * 64 + 8 * i8]);

  // 32-wide main loop: 4 idx loads + 4 gathers per stream, 16 gathers in flight
  while ((c0 + 32 <= e0) | (c1 + 32 <= e1) | (c2 + 32 <= e2) | (c3 + 32 <= e3)) {
    const bool d0 = (c0 + 32 <= e0);
    const bool d1 = (c1 + 32 <= e1);
    const bool d2 = (c2 + 32 <= e2);
    const bool d3 = (c3 + 32 <= e3);
    int n0a=0,n0b=0,n0c=0,n0d=0, n1a=0,n1b=0,n1c=0,n1d=0;
    int n2a=0,n2b=0,n2c=0,n2d=0, n3a=0,n3b=0,n3c=0,n3d=0;
    if (d0) { n0a=idx[c0+g8]; n0b=idx[c0+8+g8]; n0c=idx[c0+16+g8]; n0d=idx[c0+24+g8]; }
    if (d1) { n1a=idx[c1+g8]; n1b=idx[c1+8+g8]; n1c=idx[c1+16+g8]; n1d=idx[c1+24+g8]; }
    if (d2) { n2a=idx[c2+g8]; n2b=idx[c2+8+g8]; n2c=idx[c2+16+g8]; n2d=idx[c2+24+g8]; }
    if (d3) { n3a=idx[c3+g8]; n3b=idx[c3+8+g8]; n3c=idx[c3+16+g8]; n3d=idx[c3+24+g8]; }
    uint4 u0a,u0b,u0c,u0d, u1a,u1b,u1c,u1d, u2a,u2b,u2c,u2d, u3a,u3b,u3c,u3d;
    if (d0) { u0a=*(const uint4*)&x[(size_t)n0a*64+8*i8]; u0b=*(const uint4*)&x[(size_t)n0b*64+8*i8];
              u0c=*(const uint4*)&x[(size_t)n0c*64+8*i8]; u0d=*(const uint4*)&x[(size_t)n0d*64+8*i8]; }
    if (d1) { u1a=*(const uint4*)&x[(size_t)n1a*64+8*i8]; u1b=*(const uint4*)&x[(size_t)n1b*64+8*i8];
              u1c=*(const uint4*)&x[(size_t)n1c*64+8*i8]; u1d=*(const uint4*)&x[(size_t)n1d*64+8*i8]; }
    if (d2) { u2a=*(const uint4*)&x[(size_t)n2a*64+8*i8]; u2b=*(const uint4*)&x[(size_t)n2b*64+8*i8];
              u2c=*(const uint4*)&x[(size_t)n2c*64+8*i8]; u2d=*(const uint4*)&x[(size_t)n2d*64+8*i8]; }
    if (d3) { u3a=*(const uint4*)&x[(size_t)n3a*64+8*i8]; u3b=*(const uint4*)&x[(size_t)n3b*64+8*i8];
              u3c=*(const uint4*)&x[(size_t)n3c*64+8*i8]; u3d=*(const uint4*)&x[(size_t)n3d*64+8*i8]; }
    if (d0) { acc8(a0,u0a); acc8(a0,u0b); acc8(a0,u0c); acc8(a0,u0d); c0 += 32; }
    if (d1) { acc8(a1,u1a); acc8(a1,u1b); acc8(a1,u1c); acc8(a1,u1d); c1 += 32; }
    if (d2) { acc8(a2,u2a); acc8(a2,u2b); acc8(a2,u2c); acc8(a2,u2d); c2 += 32; }
    if (d3) { acc8(a3,u3a); acc8(a3,u3b); acc8(a3,u3c); acc8(a3,u3d); c3 += 32; }
  }
  // 16-wide pass
  {
    const bool d0 = (c0 + 16 <= e0);
    const bool d1 = (c1 + 16 <= e1);
    const bool d2 = (c2 + 16 <= e2);
    const bool d3 = (c3 + 16 <= e3);
    int n0a=0,n0b=0, n1a=0,n1b=0, n2a=0,n2b=0, n3a=0,n3b=0;
    if (d0) { n0a = idx[c0 + g8]; n0b = idx[c0 + 8 + g8]; }
    if (d1) { n1a = idx[c1 + g8]; n1b = idx[c1 + 8 + g8]; }
    if (d2) { n2a = idx[c2 + g8]; n2b = idx[c2 + 8 + g8]; }
    if (d3) { n3a = idx[c3 + g8]; n3b = idx[c3 + 8 + g8]; }
    uint4 u0a,u0b,u1a,u1b,u2a,u2b,u3a,u3b;
    if (d0) { u0a=*(const uint4*)&x[(size_t)n0a*64+8*i8]; u0b=*(const uint4*)&x[(size_t)n0b*64+8*i8]; }
    if (d1) { u1a=*(const uint4*)&x[(size_t)n1a*64+8*i8]; u1b=*(const uint4*)&x[(size_t)n1b*64+8*i8]; }
    if (d2) { u2a=*(const uint4*)&x[(size_t)n2a*64+8*i8]; u2b=*(const uint4*)&x[(size_t)n2b*64+8*i8]; }
    if (d3) { u3a=*(const uint4*)&x[(size_t)n3a*64+8*i8]; u3b=*(const uint4*)&x[(size_t)n3b*64+8*i8]; }
    if (d0) { acc8(a0,u0a); acc8(a0,u0b); c0 += 16; }
    if (d1) { acc8(a1,u1a); acc8(a1,u1b); c1 += 16; }
    if (d2) { acc8(a2,u2a); acc8(a2,u2b); c2 += 16; }
    if (d3) { acc8(a3,u3a); acc8(a3,u3b); c3 += 16; }
  }
  // 8-wide pass
  {
    const bool d0 = (c0 + 8 <= e0);
    const bool d1 = (c1 + 8 <= e1);
    const bool d2 = (c2 + 8 <= e2);
    const bool d3 = (c3 + 8 <= e3);
    int n0 = 0, n1 = 0, n2 = 0, n3 = 0;
    if (d0) n0 = idx[c0 + g8];
    if (d1) n1 = idx[c1 + g8];
    if (d2) n2 = idx[c2 + g8];
    if (d3) n3 = idx[c3 + g8];
    uint4 u0, u1, u2, u3;
    if (d0) u0 = *(const uint4*)&x[(size_t)n0 * 64 + 8 * i8];
    if (d1) u1 = *(const uint4*)&x[(size_t)n1 * 64 + 8 * i8];
    if (d2) u2 = *(const uint4*)&x[(size_t)n2 * 64 + 8 * i8];
    if (d3) u3 = *(const uint4*)&x[(size_t)n3 * 64 + 8 * i8];
    if (d0) { acc8(a0, u0); c0 += 8; }
    if (d1) { acc8(a1, u1); c1 += 8; }
    if (d2) { acc8(a2, u2); c2 += 8; }
    if (d3) { acc8(a3, u3); c3 += 8; }
  }
  // remainder (< 8 per stream)
  {
    const int rem0 = e0 - c0;
    const int rem1 = e1 - c1;
    const int rem2 = e2 - c2;
    const int rem3 = e3 - c3;
    int n0 = 0, n1 = 0, n2 = 0, n3 = 0;
    if (g8 < rem0) n0 = idx[c0 + g8];
    if (g8 < rem1) n1 = idx[c1 + g8];
    if (g8 < rem2) n2 = idx[c2 + g8];
    if (g8 < rem3) n3 = idx[c3 + g8];
    uint4 u0, u1, u2, u3;
    if (g8 < rem0) u0 = *(const uint4*)&x[(size_t)n0 * 64 + 8 * i8];
    if (g8 < rem1) u1 = *(const uint4*)&x[(size_t)n1 * 64 + 8 * i8];
    if (g8 < rem2) u2 = *(const uint4*)&x[(size_t)n2 * 64 + 8 * i8];
    if (g8 < rem3) u3 = *(const uint4*)&x[(size_t)n3 * 64 + 8 * i8];
    if (g8 < rem0) acc8(a0, u0);
    if (g8 < rem1) acc8(a1, u1);
    if (g8 < rem2) acc8(a2, u2);
    if (g8 < rem3) acc8(a3, u3);
  }

  // fold neighbor-slot groups (g8) -> lanes 0..7 hold the row sums
#pragma unroll
  for (int k = 0; k < 8; ++k) {
#pragma unroll
    for (int o = 8; o <= 32; o <<= 1) {
      a0[k] += __shfl_xor(a0[k], o, 64);
      a1[k] += __shfl_xor(a1[k], o, 64);
      a2[k] += __shfl_xor(a2[k], o, 64);
      a3[k] += __shfl_xor(a3[k], o, 64);
    }
  }
  if (g8 == 0) {
    __half hv[8];
#pragma unroll
    for (int k = 0; k < 8; ++k) hv[k] = __float2half(a0[k]);
    *(uint4*)&AsH[w * 4 + 0][8 * i8] = *(uint4*)hv;
#pragma unroll
    for (int k = 0; k < 8; ++k) hv[k] = __float2half(a1[k]);
    *(uint4*)&AsH[w * 4 + 1][8 * i8] = *(uint4*)hv;
#pragma unroll
    for (int k = 0; k < 8; ++k) hv[k] = __float2half(a2[k]);
    *(uint4*)&AsH[w * 4 + 2][8 * i8] = *(uint4*)hv;
#pragma unroll
    for (int k = 0; k < 8; ++k) hv[k] = __float2half(a3[k]);
    *(uint4*)&AsH[w * 4 + 3][8 * i8] = *(uint4*)hv;
  }
  __syncthreads();

  // ---- MFMA phase: wave w computes rows 0..15 x cols [16w, 16w+16) ----
  v4f acc = (v4f){0.f, 0.f, 0.f, 0.f};
#pragma unroll
  for (int hh = 0; hh < 2; ++hh) {
    v8h af = *(const v8h*)&AsH[i][hh * 32 + q * 8];
    v8h bf = *(const v8h*)&BT[(size_t)(w * 16 + i) * 64 + hh * 32 + q * 8];
    acc = __builtin_amdgcn_mfma_f32_16x16x32_f16(af, bf, acc, 0, 0, 0);
  }

  const int col = w * 16 + i;
  float s = 0.f, qq = 0.f;
#pragma unroll
  for (int j = 0; j < 4; ++j) {
    int row = rblk + 4 * q + j;
    if (row >= M) continue;
    float v = h2f(fmaxf(acc[j] + bias[col], 0.f));
    h[(size_t)row * 64 + col] = __float2half(v);
    s += v;
    qq += v * v;
  }
  s  += __shfl_xor(s, 16, 64);  qq += __shfl_xor(qq, 16, 64);
  s  += __shfl_xor(s, 32, 64);  qq += __shfl_xor(qq, 32, 64);
  if (q == 0) {
    const int bkt = (blockIdx.x & (NBUCKET - 1)) * 128;
    atomicAdd(&gstatP[bkt + col], s);
    atomicAdd(&gstatP[bkt + 64 + col], qq);
  }
}

// ---------------------------------------------------------------------------
// K2 (64-row tile, MFMA): Xout = relu(BN(h) @ W2 + b2), col63 = 0.
// Prologue reduces the NBUCKET BN-stat buckets. Optional fused zchain
// epilogue (last layer).
// ---------------------------------------------------------------------------
__global__ __launch_bounds__(256) void k_layer2(
    const __half* __restrict__ A, const __half* __restrict__ BT,
    const float* __restrict__ bias,
    const float* __restrict__ gstat, const float* __restrict__ gamma,
    const float* __restrict__ beta,
    __half* __restrict__ Xout, int M,
    const __half* __restrict__ Z0, const __half* __restrict__ Z1,
    const __half* __restrict__ Z2, __half* __restrict__ Xh, int doZ)
{
  __shared__ float scl_s[64], shf_s[64];
  __shared__ float tmp[128];
  const int tid  = threadIdx.x;
  const int w    = tid >> 6;
  const int lane = tid & 63;
  const int q    = lane >> 4;
  const int i    = lane & 15;
  const int rblk = blockIdx.x * 64;
  const int arow = rblk + w * 16 + i;

  if (tid < 128) {
    float a = 0.f;
#pragma unroll
    for (int b2 = 0; b2 < NBUCKET; ++b2) a += gstat[b2 * 128 + tid];
    tmp[tid] = a;
  }
  __syncthreads();
  if (tid < 64) {
    float mu  = tmp[tid] / (float)M;
    float var = tmp[64 + tid] / (float)M - mu * mu;
    float sv  = gamma[tid] / sqrtf(var + BN_EPS_F);
    scl_s[tid] = sv;
    shf_s[tid] = beta[tid] - mu * sv;
  }
  __syncthreads();

  v4f acc[4];
#pragma unroll
  for (int t = 0; t < 4; ++t) acc[t] = (v4f){0.f, 0.f, 0.f, 0.f};
#pragma unroll
  for (int hh = 0; hh < 2; ++hh) {
    const int k0 = hh * 32 + q * 8;
    v8h af = (v8h){0, 0, 0, 0, 0, 0, 0, 0};
    {
      float hv[8] = {0,0,0,0,0,0,0,0};
      if (arow < M) {
        uint4 u = *(const uint4*)&A[(size_t)arow * 64 + k0];
        __half2 h0 = *(__half2*)&u.x;
        __half2 h1 = *(__half2*)&u.y;
        __half2 h2 = *(__half2*)&u.z;
        __half2 h3 = *(__half2*)&u.w;
        hv[0] = __low2float(h0); hv[1] = __high2float(h0);
        hv[2] = __low2float(h1); hv[3] = __high2float(h1);
        hv[4] = __low2float(h2); hv[5] = __high2float(h2);
        hv[6] = __low2float(h3); hv[7] = __high2float(h3);
      }
#pragma unroll
      for (int k = 0; k < 8; ++k)
        af[k] = (_Float16)fmaf(hv[k], scl_s[k0 + k], shf_s[k0 + k]);
    }
#pragma unroll
    for (int t = 0; t < 4; ++t) {
      v8h bf = *(const v8h*)&BT[(size_t)(t * 16 + i) * 64 + k0];
      acc[t] = __builtin_amdgcn_mfma_f32_16x16x32_f16(af, bf, acc[t], 0, 0, 0);
    }
  }

#pragma unroll
  for (int j = 0; j < 4; ++j) {
    int row = rblk + w * 16 + 4 * q + j;
    if (row >= M) continue;
#pragma unroll
    for (int t = 0; t < 4; ++t) {
      float v = fmaxf(acc[t][j] + bias[i + 16 * t], 0.f);
      if (i == 15 && t == 3) v = 0.f;   // col 63
      Xout[(size_t)row * 64 + i + 16 * t] = __float2half(v);
    }
  }

  if (doZ) {
    __syncthreads();                     // all rows of this block written
    const int g16  = tid >> 4;           // 16 groups of 16 lanes
    const int il   = tid & 15;
#pragma unroll
    for (int p = 0; p < 4; ++p) {
      int row = rblk + p * 16 + g16;
      zchain_row(row, il, row < M, Z0, Z1, Z2, Xout, Xh);
    }
  }
}

// ---------------------------------------------------------------------------
// Per-graph pooling (from Xh fp16, rows gstart[g]..gstart[g+1]) + MLP head
// ---------------------------------------------------------------------------
__global__ __launch_bounds__(128) void k_mlp(const __half* __restrict__ Xh,
                                             const int* __restrict__ gstart,
                                             const float* __restrict__ fc1W, const float* __restrict__ fc1b,
                                             const float* __restrict__ fc2W, const float* __restrict__ fc2b,
                                             const float* __restrict__ fc3W, const float* __restrict__ fc3b,
                                             float* __restrict__ out) {
  __shared__ float p2s[2][64];
  __shared__ float p[64], o1[128], o2[64], lg[10], red[2];
  int g = blockIdx.x, t = threadIdx.x;
  int beg = gstart[g], end = gstart[g + 1];
  {
    int half = t >> 6, c = t & 63;
    float a = 0.f;
    int r = beg + half;
    for (; r + 6 <= end; r += 8) {
      float v0 = __half2float(Xh[(size_t)(r + 0) * 64 + c]);
      float v1 = __half2float(Xh[(size_t)(r + 2) * 64 + c]);
      float v2 = __half2float(Xh[(size_t)(r + 4) * 64 + c]);
      float v3 = __half2float(Xh[(size_t)(r + 6) * 64 + c]);
      a += (v0 + v1) + (v2 + v3);
    }
    for (; r < end; r += 2) a += __half2float(Xh[(size_t)r * 64 + c]);
    p2s[half][c] = a;
  }
  __syncthreads();
  if (t < 64) p[t] = p2s[0][t] + p2s[1][t];
  __syncthreads();
  {
    float a = fc1b[t];
    for (int k = 0; k < 64; ++k) a = fmaf(p[k], fc1W[k * 128 + t], a);
    o1[t] = fmaxf(a, 0.f);
  }
  __syncthreads();
  if (t < 64) {
    float a = fc2b[t];
    for (int k = 0; k < 128; ++k) a = fmaf(o1[k], fc2W[k * 64 + t], a);
    o2[t] = fmaxf(a, 0.f);
  }
  __syncthreads();
  if (t < 10) {
    float a = fc3b[t];
    for (int k = 0; k < 64; ++k) a = fmaf(o2[k], fc3W[k * 10 + t], a);
    lg[t] = a;
  }
  __syncthreads();
  if (t == 0) {
    float mx = lg[0];
    for (int j = 1; j < 10; ++j) mx = fmaxf(mx, lg[j]);
    float s = 0.f;
    for (int j = 0; j < 10; ++j) s += expf(lg[j] - mx);
    red[0] = mx;
    red[1] = logf(s);
  }
  __syncthreads();
  if (t < 10) out[(size_t)g * 10 + t] = lg[t] - red[0] - red[1];
}

// ---------------------------------------------------------------------------
extern "C" void kernel_launch(void* const* d_in, const int* in_sizes, int n_in,
                              void* d_out, int out_size, void* d_ws, size_t ws_size,
                              hipStream_t stream) {
  const float* x_in  = (const float*)d_in[0];
  const int*   ei    = (const int*)d_in[1];
  const int*   batch = (const int*)d_in[2];
  const float* W0    = (const float*)d_in[3];
  const float* b0    = (const float*)d_in[4];
  const float* cW1   = (const float*)d_in[5];
  const float* cb1   = (const float*)d_in[6];
  const float* gamma = (const float*)d_in[7];
  const float* beta  = (const float*)d_in[8];
  const float* cW2   = (const float*)d_in[9];
  const float* cb2   = (const float*)d_in[10];
  const float* fc1W  = (const float*)d_in[11];
  const float* fc1b  = (const float*)d_in[12];
  const float* fc2W  = (const float*)d_in[13];
  const float* fc2b  = (const float*)d_in[14];
  const float* fc3W  = (const float*)d_in[15];
  const float* fc3b  = (const float*)d_in[16];
  float* out = (float*)d_out;

  const int N = in_sizes[0] / 128;
  const int E = in_sizes[1] / 2;
  const int L = in_sizes[5] / (64 * 64);
  const int G = out_size / 10;
  const int* src = ei;
  const int* dst = ei + E;

  char* ws = (char*)d_ws;
  size_t off = 0;
  auto alloc = [&](size_t bytes) -> char* {
    char* p = ws + off;
    off += (bytes + 255) & ~(size_t)255;
    return p;
  };
  __half* X0  = (__half*)alloc((size_t)N * 64 * 2);
  __half* X0L = (__half*)alloc((size_t)N * 64 * 2);   // laundered X0
  __half* X1  = (__half*)alloc((size_t)N * 64 * 2);
  __half* X2  = (__half*)alloc((size_t)N * 64 * 2);
  __half* X3  = (__half*)alloc((size_t)N * 64 * 2);
  __half* Bf  = (__half*)alloc((size_t)N * 64 * 2);
  __half* Xh  = (__half*)alloc((size_t)N * 64 * 2);
  __half* W0T = (__half*)alloc((size_t)64 * 128 * 2);
  __half* W1T = (__half*)alloc((size_t)L * 64 * 64 * 2);
  __half* W2T = (__half*)alloc((size_t)L * 64 * 64 * 2);
  int*    gstart = (int*)alloc((size_t)(G + 1) * 4);
  // ---- zeroed region: cnt, gstatAll, ovf (contiguous, zeroed by k_zero) ----
  int*   cnt  = (int*)alloc((size_t)N * 4);
  float* gstatAll = (float*)alloc((size_t)3 * NBUCKET * 128 * 4);
  int*   ovf  = (int*)alloc(256);        // one flag (padded)
  char*  zero_end = ws + off;
  // -------------------------------------------------------------------------
  unsigned short* slots = (unsigned short*)alloc((size_t)N * CAP * 2);
  int*   rowptr = (int*)alloc((size_t)(N + 1) * 4);
  int*   cursor = (int*)alloc((size_t)N * 4);
  unsigned short* csr = (unsigned short*)alloc((size_t)E * 2);
  int*   bsum   = (int*)alloc(256 * 4);
  int*   boff   = (int*)alloc(256 * 4);
  __half* Xs[4] = {X0L, X1, X2, X3};     // downstream consumers use laundered X0

  const int zwords = (int)((zero_end - (char*)cnt) / 4);

  const int perBlk    = (N + 127) >> 7;               // 16-row blocks per slice
  const int per       = perBlk * 16;                  // rows per XCD slice
  const int mmGrid    = (N + 63) / 64;
  const int l1Grid    = 8 * perBlk;                   // swizzled layer1 grid
  const int edge4Grid = (E / 4 + 255) / 256 + 1;
  const int fillGrid  = edge4Grid * 8;                // 8 XCD replicas
  const int gbGrid    = (N + 255) / 256;
  const int wBlk      = (L * 4096 + 255) / 256;
  const int nX16      = N * 64 * 2 / 16;              // uint4 count: X0
  const int packGrid  = (nX16 + 255) / 256;

  // zero cnt/gstat/ovf + convert W0T (needed by k_front's mm0 section)
  k_zero<<<256, 256, 0, stream>>>(W0, W0T, cnt, zwords);

  // fused front-end: XCD-partitioned slot-fill | mm0 | gb | W1T/W2T cvt
  k_front<<<fillGrid + mmGrid + gbGrid + wBlk, 256, 0, stream>>>(
      x_in, W0T, b0, X0, N,
      src, dst, E, cnt, slots, ovf,
      batch, G, gstart,
      cW1, cW2, L, W1T, W2T,
      per, fillGrid, mmGrid, gbGrid);

  // launder X0 (mm0's scattered 2B stores) into a clean streamed buffer
  k_pack<<<packGrid, 256, 0, stream>>>((const uint4*)X0, (uint4*)X0L, nX16);

  // overflow fallback chain (early-exit when ovf == 0)
  const int NB = (N + 255) / 256;
  k_scan1<<<NB, 256, 0, stream>>>(ovf, cnt, N, rowptr, bsum);
  k_scan2<<<1, 256, 0, stream>>>(ovf, bsum, NB, boff);
  k_scan3<<<NB, 256, 0, stream>>>(ovf, rowptr, boff, cursor, N, E);
  k_fill<<<edge4Grid, 256, 0, stream>>>(ovf, src, dst, E, cursor, csr);

  for (int i = 0; i < L; ++i) {
    float* gstat = gstatAll + (size_t)i * NBUCKET * 128;
    const int doZ = (i == L - 1) ? 1 : 0;
    k_layer1<<<l1Grid, 256, 0, stream>>>(Xs[i], ovf, cnt, slots, rowptr, csr,
                                         W1T + (size_t)i * 4096, cb1 + i * 64,
                                         Bf, gstat, perBlk, N);
    k_layer2<<<mmGrid, 256, 0, stream>>>(Bf, W2T + (size_t)i * 4096, cb2 + i * 64,
                                         gstat, gamma + i * 64, beta + i * 64,
                                         Xs[i + 1], N,
                                         Xs[0], X1, X2, Xh, doZ);
  }

  k_mlp<<<G, 128, 0, stream>>>(Xh, gstart, fc1W, fc1b, fc2W, fc2b, fc3W, fc3b, out);
}